// Round 16
// baseline (2576.128 us; speedup 1.0000x reference)
//
#include <hip/hip_runtime.h>
#include <hip/hip_bf16.h>
#include <math.h>

#define Bb   4
#define Tt   1024
#define Cc   768
#define Hh   12
#define Dd   64
#define Ll   12
#define Vv   10000
#define WTEe 704
#define MTOT 4096   // B*T

// Q pre-scale: 1/sqrt(64) * log2(e)  (attention uses exp2)
#define QSCALE 0.18033688f

typedef __bf16 bf16x8 __attribute__((ext_vector_type(8)));
typedef float  f32x4  __attribute__((ext_vector_type(4)));
typedef unsigned short u16;

typedef const __attribute__((address_space(1))) void* gptr_t;
typedef __attribute__((address_space(3))) void* lptr_t;

__device__ inline void gload16(const void* g, void* l) {
    __builtin_amdgcn_global_load_lds((gptr_t)g, (lptr_t)l, 16, 0, 0);
}

__device__ inline u16 f2bf(float f) {
    unsigned int u = __float_as_uint(f);
    return (u16)((u + 0x7fffu + ((u >> 16) & 1u)) >> 16);   // RNE
}
__device__ inline float bf2f(u16 u) { return __uint_as_float(((unsigned)u) << 16); }

__device__ inline float gelu_f(float v) {
    float t = v * (0.797884561f + 0.0356774081f * v * v);
    float e = __expf(2.f * t);
    float th = 1.f - 2.f / (e + 1.f);
    return 0.5f * v * (1.f + th);
}

#if __has_builtin(__builtin_amdgcn_exp2f)
__device__ inline float fast_exp2(float x) { return __builtin_amdgcn_exp2f(x); }
#else
__device__ inline float fast_exp2(float x) { return exp2f(x); }
#endif

#define WAITVM(N)  asm volatile("s_waitcnt vmcnt(" #N ")" ::: "memory")
#define WAITLGKM0() asm volatile("s_waitcnt lgkmcnt(0)" ::: "memory")
#define SCHEDB()   __builtin_amdgcn_sched_barrier(0)
#define SBAR()     __builtin_amdgcn_s_barrier()

// ---------------------------------------------------------------------------
// Weight pack: f32 [Nall][K] row-major -> bf16 fragment blocks.
// Block = 16 rows x 32 cols, bi = (row/16)*(K/32) + col/32; within block
// lane l = (row&15) | (((col>>3)&3)<<4) holds 8 elems.
// ---------------------------------------------------------------------------
__global__ __launch_bounds__(256)
void convert_pack(const float* __restrict__ in, u16* __restrict__ out,
                  int nk8, int K, int rowmod, int scaleLim)
{
    int i = blockIdx.x * 256 + threadIdx.x;
    if (i >= nk8) return;
    int row = (i << 3) / K;
    int col = (i << 3) % K;
    float s = 1.f;
    if (rowmod && (row % rowmod) < scaleLim) s = QSCALE;
    float4 v0 = ((const float4*)in)[2 * i];
    float4 v1 = ((const float4*)in)[2 * i + 1];
    uint4 o;
    o.x = (unsigned)f2bf(v0.x * s) | ((unsigned)f2bf(v0.y * s) << 16);
    o.y = (unsigned)f2bf(v0.z * s) | ((unsigned)f2bf(v0.w * s) << 16);
    o.z = (unsigned)f2bf(v1.x * s) | ((unsigned)f2bf(v1.y * s) << 16);
    o.w = (unsigned)f2bf(v1.z * s) | ((unsigned)f2bf(v1.w * s) << 16);
    int tile = row >> 4, kt = col >> 5;
    int l = (row & 15) | (((col >> 3) & 3) << 4);
    size_t off = (((size_t)tile * (K >> 5) + kt) << 9) + l * 8;
    *(uint4*)(out + off) = o;
}

// qkv bias with Q prescale
__global__ __launch_bounds__(256)
void scale_qkvb(const float* __restrict__ in, float* __restrict__ out, int n)
{
    int i = blockIdx.x * 256 + threadIdx.x;
    if (i >= n) return;
    int col = i % (3 * Cc);
    out[i] = in[i] * (col < Cc ? QSCALE : 1.f);
}

// ---------------------------------------------------------------------------
// Embedding (f32 residual stream)
// ---------------------------------------------------------------------------
__global__ __launch_bounds__(256)
void embed_kernel(const int* __restrict__ idx, const float* __restrict__ ts,
                  const float* __restrict__ wte, const float* __restrict__ freq,
                  const float* __restrict__ ph, const float* __restrict__ wpe,
                  float* __restrict__ x)
{
    const int bt  = blockIdx.x;
    const int t   = bt & (Tt - 1);
    const int tok = idx[bt];
    const float tv = ts[bt];
#pragma unroll
    for (int j = 0; j < 3; ++j) {
        int c = threadIdx.x + (j << 8);
        float val;
        if (c < WTEe) val = wte[(size_t)tok * WTEe + c];
        else {
            int e = c - WTEe;
            val = cosf(tv * freq[e] + ph[e]);
        }
        x[(size_t)bt * Cc + c] = val + wpe[(size_t)t * Cc + c];
    }
}

// ---------------------------------------------------------------------------
// LayerNorm -> PACKED-A output. 16 rows per block (grid MTOT/16).
// ---------------------------------------------------------------------------
__global__ __launch_bounds__(256)
void ln_pack16(const float* __restrict__ x, const float* __restrict__ wt,
               const float* __restrict__ bs, u16* __restrict__ out)
{
    __shared__ float mus[16], rss[16];
    const int tid  = threadIdx.x;
    const int lane = tid & 63;
    const int w    = tid >> 6;
    const int tile = blockIdx.x;
    const int r0   = tile << 4;

#pragma unroll
    for (int rr = 0; rr < 4; ++rr) {
        const int row = r0 + w * 4 + rr;
        const float* xr = x + (size_t)row * Cc;
        float s = 0.f, s2 = 0.f;
#pragma unroll
        for (int j = 0; j < 12; ++j) {
            float v = xr[lane + (j << 6)];
            s += v; s2 += v * v;
        }
#pragma unroll
        for (int m = 32; m; m >>= 1) {
            s  += __shfl_xor(s, m);
            s2 += __shfl_xor(s2, m);
        }
        if (lane == 0) {
            float mu = s * (1.f / 768.f);
            float var = s2 * (1.f / 768.f) - mu * mu;
            mus[w * 4 + rr] = mu;
            rss[w * 4 + rr] = rsqrtf(var + 1e-5f);
        }
    }
    __syncthreads();

    u16* ob = out + ((size_t)tile * 24 << 9);
#pragma unroll
    for (int it = 0; it < 6; ++it) {
        int c   = tid + (it << 8);
        int kt  = c >> 6, l = c & 63;
        int row = l & 15, g = l >> 4;
        int col = kt * 32 + g * 8;
        float mu = mus[row], rs = rss[row];
        const float* xp = x + (size_t)(r0 + row) * Cc + col;
        float4 a = *(const float4*)xp;
        float4 bq = *(const float4*)(xp + 4);
        ushort o[8];
        o[0] = f2bf((a.x - mu) * rs * wt[col]     + bs[col]);
        o[1] = f2bf((a.y - mu) * rs * wt[col + 1] + bs[col + 1]);
        o[2] = f2bf((a.z - mu) * rs * wt[col + 2] + bs[col + 2]);
        o[3] = f2bf((a.w - mu) * rs * wt[col + 3] + bs[col + 3]);
        o[4] = f2bf((bq.x - mu) * rs * wt[col + 4] + bs[col + 4]);
        o[5] = f2bf((bq.y - mu) * rs * wt[col + 5] + bs[col + 5]);
        o[6] = f2bf((bq.z - mu) * rs * wt[col + 6] + bs[col + 6]);
        o[7] = f2bf((bq.w - mu) * rs * wt[col + 7] + bs[col + 7]);
        *(uint4*)(ob + ((size_t)kt << 9) + l * 8) = *(uint4*)o;
    }
}

// ---------------------------------------------------------------------------
// Unified 64x128 bf16 GEMM, BK=64, packed-B, optionally packed-A.
// Double-buffered 48 KB (3 blocks/CU), 4 waves, wave tile 32x64.
// 16 MFMA + 12 ds_read per k-step; 6 gloads/wave/stage; own-wave WAITVM(0)
// precedes the single end-of-iter barrier.
// EPI: 0 bias, 1 bias+f32 resid, 2 bias+GELU, 3 qkv (V cols -> vt[b,h,d,T])
// ---------------------------------------------------------------------------
__device__ inline void st_out(float* p, size_t o, float v) { p[o] = v; }
__device__ inline void st_out(u16*   p, size_t o, float v) { p[o] = f2bf(v); }

template<int EPI, int APK, typename OutT>
__global__ __launch_bounds__(256)
void gemm_nk64(const u16* __restrict__ A, const u16* __restrict__ Wp,
               const float* __restrict__ bias, const float* __restrict__ resid,
               OutT* __restrict__ out, u16* __restrict__ vt, int N, int K)
{
    __shared__ uint4 AF[2][8][64];    // [buf][mt*2+slab]  16 KB
    __shared__ uint4 BF[2][16][64];   // [buf][nt*2+slab]  32 KB
    const int tid  = threadIdx.x;
    const int lane = tid & 63;
    const int w    = tid >> 6;
    const int wr   = w & 1, wc = w >> 1;
    const int lq   = lane & 15, g = lane >> 4;
    const int m0   = blockIdx.x * 64, n0 = blockIdx.y * 128;
    const int KB   = K >> 5;
    const int nk   = K >> 6;

    const u16* ap;
    if (APK) ap = A + ((((size_t)(m0 >> 4) + w) * KB) << 9) + lane * 8;
    else     ap = A + (size_t)(m0 + w * 16 + lq) * K + g * 8;

    int tn0 = (n0 >> 4) + 2 * w, tn1 = tn0 + 1;
    const int tmax = (N >> 4) - 1;
    tn0 = tn0 < tmax ? tn0 : tmax;
    tn1 = tn1 < tmax ? tn1 : tmax;
    const u16* bq0 = Wp + (((size_t)tn0 * KB) << 9) + lane * 8;
    const u16* bq1 = Wp + (((size_t)tn1 * KB) << 9) + lane * 8;

    f32x4 acc[2][4] = {};

#define GSTAGE(t, bi) do {                                                 \
        if (APK) {                                                         \
            gload16(ap + ((size_t)(2 * (t)) << 9),     &AF[bi][2 * w][lane]); \
            gload16(ap + ((size_t)(2 * (t) + 1) << 9), &AF[bi][2 * w + 1][lane]); \
        } else {                                                           \
            gload16(ap + ((t) << 6),      &AF[bi][2 * w][lane]);           \
            gload16(ap + ((t) << 6) + 32, &AF[bi][2 * w + 1][lane]);       \
        }                                                                  \
        gload16(bq0 + ((size_t)(2 * (t)) << 9),     &BF[bi][4 * w][lane]); \
        gload16(bq0 + ((size_t)(2 * (t) + 1) << 9), &BF[bi][4 * w + 1][lane]); \
        gload16(bq1 + ((size_t)(2 * (t)) << 9),     &BF[bi][4 * w + 2][lane]); \
        gload16(bq1 + ((size_t)(2 * (t) + 1) << 9), &BF[bi][4 * w + 3][lane]); } while (0)

    GSTAGE(0, 0);
    WAITVM(0);
    SCHEDB();
    SBAR();
    SCHEDB();

    for (int t = 0; t < nk; ++t) {
        const int buf = t & 1;
        if (t + 1 < nk) GSTAGE(t + 1, buf ^ 1);

#pragma unroll
        for (int s = 0; s < 2; ++s) {
            bf16x8 a0 = __builtin_bit_cast(bf16x8, AF[buf][(wr * 2) * 2 + s][lane]);
            bf16x8 a1 = __builtin_bit_cast(bf16x8, AF[buf][(wr * 2 + 1) * 2 + s][lane]);
            bf16x8 bb[4];
#pragma unroll
            for (int ni = 0; ni < 4; ++ni)
                bb[ni] = __builtin_bit_cast(bf16x8, BF[buf][(wc * 4 + ni) * 2 + s][lane]);
            __builtin_amdgcn_s_setprio(1);
#pragma unroll
            for (int ni = 0; ni < 4; ++ni) {
                acc[0][ni] = __builtin_amdgcn_mfma_f32_16x16x32_bf16(
                    a0, bb[ni], acc[0][ni], 0, 0, 0);
                acc[1][ni] = __builtin_amdgcn_mfma_f32_16x16x32_bf16(
                    a1, bb[ni], acc[1][ni], 0, 0, 0);
            }
            __builtin_amdgcn_s_setprio(0);
        }

        WAITVM(0);     // own 6 staged loads; issued a full phase earlier
        SCHEDB();
        SBAR();
        SCHEDB();
    }
#undef GSTAGE

    if (EPI == 3 && n0 >= 1536) {        // V block -> transposed vt[b,h,d,T]
#pragma unroll
        for (int mi = 0; mi < 2; ++mi)
#pragma unroll
            for (int ni = 0; ni < 4; ++ni) {
                int col = n0 + wc * 64 + ni * 16 + lq;
                int c2  = col - 1536;
                int hh  = c2 >> 6, dd = c2 & 63;
                int row = m0 + (wr * 2 + mi) * 16 + g * 4;
                int bb  = row >> 10, tr = row & 1023;
                float bv = bias[col];
                ushort4 o;
                o.x = f2bf(acc[mi][ni][0] + bv);
                o.y = f2bf(acc[mi][ni][1] + bv);
                o.z = f2bf(acc[mi][ni][2] + bv);
                o.w = f2bf(acc[mi][ni][3] + bv);
                *(ushort4*)&vt[(((size_t)bb * Hh + hh) * Dd + dd) * Tt + tr] = o;
            }
        return;
    }

#pragma unroll
    for (int mi = 0; mi < 2; ++mi)
#pragma unroll
        for (int ni = 0; ni < 4; ++ni) {
            int col = n0 + wc * 64 + ni * 16 + lq;
            if (col >= N) continue;
            int row = m0 + (wr * 2 + mi) * 16 + g * 4;
            float bv = bias ? bias[col] : 0.f;
#pragma unroll
            for (int q = 0; q < 4; ++q) {
                float v = acc[mi][ni][q] + bv;
                size_t o = (size_t)(row + q) * N + col;
                if (EPI == 1) v += resid[o];
                if (EPI == 2) v = gelu_f(v);
                st_out(out, o, v);
            }
        }
}

// ---------------------------------------------------------------------------
// 256x256 8-phase bf16 GEMM, packed-A + packed-B — lm_head only. 2D grid.
// ---------------------------------------------------------------------------
template<int EPI, typename OutT>
__global__ __launch_bounds__(512, 2)
void gemm8p(const u16* __restrict__ Apk, const u16* __restrict__ Wp,
            const float* __restrict__ bias, const float* __restrict__ resid,
            OutT* __restrict__ out, int N, int K)
{
    __shared__ uint4 AF[2][16][2][64];
    __shared__ uint4 BF[2][16][2][64];
    const int tid  = threadIdx.x;
    const int lane = tid & 63;
    const int w    = tid >> 6;
    const int wr   = w >> 2, wc = w & 3;
    const int lq   = lane & 15, g = lane >> 4;
    const int m0   = blockIdx.x * 256, n0 = blockIdx.y * 256;
    const int KB   = K >> 5;

    const u16* aq0 = Apk + ((((size_t)(m0 >> 4) + 2 * w) * KB) << 9) + lane * 8;
    const u16* aq1 = aq0 + ((size_t)KB << 9);

    int tn0 = (n0 >> 4) + 2 * w, tn1 = tn0 + 1;
    const int tmax = (N >> 4) - 1;
    tn0 = tn0 < tmax ? tn0 : tmax;
    tn1 = tn1 < tmax ? tn1 : tmax;
    const u16* bq0 = Wp + (((size_t)tn0 * KB) << 9) + lane * 8;
    const u16* bq1 = Wp + (((size_t)tn1 * KB) << 9) + lane * 8;

    f32x4 acc[8][4] = {};
    const int nt = K >> 6;

    gload16(aq0,       &AF[0][2 * w][0][lane]);
    gload16(aq1,       &AF[0][2 * w + 1][0][lane]);
    gload16(bq0,       &BF[0][2 * w][0][lane]);
    gload16(bq1,       &BF[0][2 * w + 1][0][lane]);
    gload16(aq0 + 512, &AF[0][2 * w][1][lane]);
    gload16(aq1 + 512, &AF[0][2 * w + 1][1][lane]);
    gload16(bq0 + 512, &BF[0][2 * w][1][lane]);
    gload16(bq1 + 512, &BF[0][2 * w + 1][1][lane]);
    WAITVM(0);
    SCHEDB();
    SBAR();

    int buf = 0;
    for (int t = 0; t < nt; ++t) {
        const bool more = (t + 1 < nt);
        const size_t bb0 = (size_t)(2 * (t + 1)) << 9;
        bf16x8 a0[4], a1[4], b0[4];

#pragma unroll
        for (int i = 0; i < 4; ++i)
            a0[i] = __builtin_bit_cast(bf16x8, AF[buf][wr * 8 + i][0][lane]);
#pragma unroll
        for (int i = 0; i < 4; ++i)
            b0[i] = __builtin_bit_cast(bf16x8, BF[buf][wc * 4 + i][0][lane]);
        if (more) {
            gload16(aq0 + bb0, &AF[buf ^ 1][2 * w][0][lane]);
            gload16(aq1 + bb0, &AF[buf ^ 1][2 * w + 1][0][lane]);
        }
        SCHEDB();
        SBAR();
        WAITLGKM0();
        SCHEDB();
        __builtin_amdgcn_s_setprio(1);
#pragma unroll
        for (int mi = 0; mi < 4; ++mi)
#pragma unroll
            for (int ni = 0; ni < 4; ++ni)
                acc[mi][ni] = __builtin_amdgcn_mfma_f32_16x16x32_bf16(
                    a0[mi], b0[ni], acc[mi][ni], 0, 0, 0);
        __builtin_amdgcn_s_setprio(0);
        SBAR();

#pragma unroll
        for (int i = 0; i < 4; ++i)
            a1[i] = __builtin_bit_cast(bf16x8, AF[buf][wr * 8 + 4 + i][0][lane]);
        if (more) {
            gload16(bq0 + bb0, &BF[buf ^ 1][2 * w][0][lane]);
            gload16(bq1 + bb0, &BF[buf ^ 1][2 * w + 1][0][lane]);
        }
        SCHEDB();
        SBAR();
        WAITLGKM0();
        SCHEDB();
        __builtin_amdgcn_s_setprio(1);
#pragma unroll
        for (int mi = 0; mi < 4; ++mi)
#pragma unroll
            for (int ni = 0; ni < 4; ++ni)
                acc[4 + mi][ni] = __builtin_amdgcn_mfma_f32_16x16x32_bf16(
                    a1[mi], b0[ni], acc[4 + mi][ni], 0, 0, 0);
        __builtin_amdgcn_s_setprio(0);
        if (more) { WAITVM(4); } else { WAITVM(0); }
        SCHEDB();
        SBAR();

#pragma unroll
        for (int i = 0; i < 4; ++i)
            a0[i] = __builtin_bit_cast(bf16x8, AF[buf][wr * 8 + i][1][lane]);
#pragma unroll
        for (int i = 0; i < 4; ++i)
            b0[i] = __builtin_bit_cast(bf16x8, BF[buf][wc * 4 + i][1][lane]);
        if (more) {
            gload16(aq0 + bb0 + 512, &AF[buf ^ 1][2 * w][1][lane]);
            gload16(aq1 + bb0 + 512, &AF[buf ^ 1][2 * w + 1][1][lane]);
        }
        SCHEDB();
        SBAR();
        WAITLGKM0();
        SCHEDB();
        __builtin_amdgcn_s_setprio(1);
#pragma unroll
        for (int mi = 0; mi < 4; ++mi)
#pragma unroll
            for (int ni = 0; ni < 4; ++ni)
                acc[mi][ni] = __builtin_amdgcn_mfma_f32_16x16x32_bf16(
                    a0[mi], b0[ni], acc[mi][ni], 0, 0, 0);
        __builtin_amdgcn_s_setprio(0);
        SBAR();

#pragma unroll
        for (int i = 0; i < 4; ++i)
            a1[i] = __builtin_bit_cast(bf16x8, AF[buf][wr * 8 + 4 + i][1][lane]);
        if (more) {
            gload16(bq0 + bb0 + 512, &BF[buf ^ 1][2 * w][1][lane]);
            gload16(bq1 + bb0 + 512, &BF[buf ^ 1][2 * w + 1][1][lane]);
        }
        SCHEDB();
        SBAR();
        WAITLGKM0();
        SCHEDB();
        __builtin_amdgcn_s_setprio(1);
#pragma unroll
        for (int mi = 0; mi < 4; ++mi)
#pragma unroll
            for (int ni = 0; ni < 4; ++ni)
                acc[4 + mi][ni] = __builtin_amdgcn_mfma_f32_16x16x32_bf16(
                    a1[mi], b0[ni], acc[4 + mi][ni], 0, 0, 0);
        __builtin_amdgcn_s_setprio(0);
        if (more) { WAITVM(4); } else { WAITVM(0); }
        SCHEDB();
        SBAR();

        buf ^= 1;
    }

#pragma unroll
    for (int mi = 0; mi < 8; ++mi)
#pragma unroll
        for (int ni = 0; ni < 4; ++ni) {
            int col = n0 + wc * 64 + ni * 16 + lq;
            if (col >= N) continue;
            int row = m0 + wr * 128 + mi * 16 + g * 4;
            float bv = bias ? bias[col] : 0.f;
#pragma unroll
            for (int q = 0; q < 4; ++q) {
                float v = acc[mi][ni][q] + bv;
                size_t o = (size_t)(row + q) * N + col;
                if (EPI == 1) v += resid[o];
                if (EPI == 2) v = gelu_f(v);
                st_out(out, o, v);
            }
        }
}

// ---------------------------------------------------------------------------
// MFMA flash attention, QBLK=128 / 8 waves, swapped QK^T (r13/r15 version).
// ---------------------------------------------------------------------------
__global__ __launch_bounds__(512)
void attn_mfma(const u16* __restrict__ qkv, const u16* __restrict__ vt,
               u16* __restrict__ y)
{
    __shared__ uint4 KF[2][4][2][64];
    __shared__ uint4 VF[2][4][2][64];

    const int tid  = threadIdx.x;
    const int lane = tid & 63;
    const int w    = tid >> 6;
    const int lq   = lane & 15, g = lane >> 4;
    const int m    = gridDim.x - 1 - blockIdx.x;   // heavy blocks first
    const int bh   = blockIdx.y;
    const int b    = bh / Hh, h = bh % Hh;
    const int wq0  = m * 128 + w * 16;
    const size_t base = (size_t)b * Tt * (3 * Cc);

    const u16* qrow = qkv + base + (size_t)(wq0 + lq) * (3 * Cc) + h * Dd;
    bf16x8 qf0 = __builtin_bit_cast(bf16x8, *(const uint4*)(qrow + g * 8));
    bf16x8 qf1 = __builtin_bit_cast(bf16x8, *(const uint4*)(qrow + 32 + g * 8));

    f32x4 yac[4] = {};
    float lrun = 0.f;

    const int wm = w & 3;
    const u16* kbase = qkv + base + Cc + h * Dd + (size_t)(wm * 16 + lq) * (3 * Cc) + g * 8;
    const u16* vbase = vt + ((size_t)bh * Dd + wm * 16 + lq) * Tt + g * 8;

#define STAGE(c, bi)  do {                                              \
        if (w < 4) {                                                    \
            const u16* kp = kbase + (size_t)(c) * 64 * (3 * Cc);        \
            gload16(kp,      &KF[bi][wm][0][lane]);                     \
            gload16(kp + 32, &KF[bi][wm][1][lane]);                     \
        } else {                                                        \
            const u16* vp = vbase + (c) * 64;                           \
            gload16(vp,      &VF[bi][wm][0][lane]);                     \
            gload16(vp + 32, &VF[bi][wm][1][lane]);                     \
        }                                                               \
    } while (0)

    const int nch = 2 * m + 2;
    STAGE(0, 0);
    WAITVM(0);
    SCHEDB();
    SBAR();

    const int srcb = lq + ((g & 1) << 5);

    int buf = 0;
    for (int c = 0; c < nch; ++c) {
        if (c + 1 < nch) STAGE(c + 1, buf ^ 1);

        f32x4 sc[4] = {};
        __builtin_amdgcn_s_setprio(1);
#pragma unroll
        for (int nt = 0; nt < 4; ++nt) {
            bf16x8 k0 = __builtin_bit_cast(bf16x8, KF[buf][nt][0][lane]);
            bf16x8 k1 = __builtin_bit_cast(bf16x8, KF[buf][nt][1][lane]);
            sc[nt] = __builtin_amdgcn_mfma_f32_16x16x32_bf16(k0, qf0, sc[nt], 0, 0, 0);
            sc[nt] = __builtin_amdgcn_mfma_f32_16x16x32_bf16(k1, qf1, sc[nt], 0, 0, 0);
        }
        __builtin_amdgcn_s_setprio(0);

        const int s0 = c * 64;
        if (s0 + 63 > wq0) {
            const int qg = wq0 + lq;
#pragma unroll
            for (int nt = 0; nt < 4; ++nt) {
                const int kb = s0 + nt * 16 + (g << 2);
#pragma unroll
                for (int j = 0; j < 4; ++j)
                    if (kb + j > qg) sc[nt][j] = -1e30f;
            }
        }

        float ls = 0.f;
#pragma unroll
        for (int nt = 0; nt < 4; ++nt)
#pragma unroll
            for (int j = 0; j < 4; ++j) {
                float p = fast_exp2(sc[nt][j]);
                sc[nt][j] = p;
                ls += p;
            }
        ls += __shfl_xor(ls, 16);
        ls += __shfl_xor(ls, 32);
        lrun += ls;

        unsigned pk[4][2];
#pragma unroll
        for (int nt = 0; nt < 4; ++nt) {
            unsigned u0 = __float_as_uint(sc[nt][0]);
            unsigned u1 = __float_as_uint(sc[nt][1]);
            unsigned u2 = __float_as_uint(sc[nt][2]);
            unsigned u3 = __float_as_uint(sc[nt][3]);
            pk[nt][0] = (u0 >> 16) | (u1 & 0xffff0000u);
            pk[nt][1] = (u2 >> 16) | (u3 & 0xffff0000u);
        }

        unsigned pa0[4], pa1[4];
#pragma unroll
        for (int m2 = 0; m2 < 4; ++m2) {
            int hsel = m2 & 1;
            int src  = srcb + ((m2 >> 1) << 4);
            unsigned lo0 = __shfl(pk[0][hsel], src);
            unsigned hi0 = __shfl(pk[1][hsel], src);
            unsigned lo1 = __shfl(pk[2][hsel], src);
            unsigned hi1 = __shfl(pk[3][hsel], src);
            pa0[m2] = (g >> 1) ? hi0 : lo0;
            pa1[m2] = (g >> 1) ? hi1 : lo1;
        }
        uint4 A0 = make_uint4(pa0[0], pa0[1], pa0[2], pa0[3]);
        uint4 A1 = make_uint4(pa1[0], pa1[1], pa1[2], pa1[3]);
        bf16x8 pA0 = __builtin_bit_cast(bf16x8, A0);
        bf16x8 pA1 = __builtin_bit_cast(bf16x8, A1);

        __builtin_amdgcn_s_setprio(1);
#pragma unroll
        for (int dt = 0; dt < 4; ++dt) {
            bf16x8 vb0 = __builtin_bit_cast(bf16x8, VF[buf][dt][0][lane]);
            bf16x8 vb1 = __builtin_bit_cast(bf16x8, VF[buf][dt][1][lane]);
            yac[dt] = __builtin_amdgcn_mfma_f32_16x16x32_bf16(pA0, vb0, yac[dt], 0, 0, 0);
            yac[dt] = __builtin_amdgcn_mfma_f32_16x16x32_bf16(pA1, vb1, yac[dt], 0, 0, 0);
        }
        __builtin_amdgcn_s_setprio(0);

        if (c + 1 < nch) { WAITVM(0); }
        SCHEDB();
        SBAR();
        buf ^= 1;
    }
#undef STAGE

    f32x4 rl;
#pragma unroll
    for (int j = 0; j < 4; ++j)
        rl[j] = 1.0f / __shfl(lrun, (g << 2) + j);
#pragma unroll
    for (int dt = 0; dt < 4; ++dt)
#pragma unroll
        for (int j = 0; j < 4; ++j)
            y[(size_t)(b * Tt + wq0 + (g << 2) + j) * Cc + h * Dd + dt * 16 + lq]
                = f2bf(yac[dt][j] * rl[j]);
}

// ---------------------------------------------------------------------------
// tpred (packed-A hB): out[row] = dot(h[row], tp_w)
// ---------------------------------------------------------------------------
__global__ __launch_bounds__(256)
void tpred_kernel(const u16* __restrict__ hp, const float* __restrict__ tp,
                  float* __restrict__ out)
{
    const int row  = blockIdx.x * 4 + (threadIdx.x >> 6);
    const int lane = threadIdx.x & 63;
    const int tile = row >> 4, r15 = row & 15;
    const u16* tb = hp + ((size_t)tile * 24 << 9);
    float s = 0.f;
#pragma unroll
    for (int j = 0; j < 12; ++j) {
        int col = lane + (j << 6);
        int kt = col >> 5, g = (col >> 3) & 3, e = col & 7;
        s += bf2f(tb[((size_t)kt << 9) + (r15 | (g << 4)) * 8 + e]) * tp[col];
    }
#pragma unroll
    for (int m = 32; m; m >>= 1) s += __shfl_xor(s, m);
    if (lane == 0) out[row] = s;
}

// ---------------------------------------------------------------------------
extern "C" void kernel_launch(void* const* d_in, const int* in_sizes, int n_in,
                              void* d_out, int out_size, void* d_ws, size_t ws_size,
                              hipStream_t stream)
{
    const int*   idx  = (const int*)d_in[0];
    const float* ts   = (const float*)d_in[1];
    const float* wte  = (const float*)d_in[2];
    const float* freq = (const float*)d_in[3];
    const float* ph   = (const float*)d_in[4];
    const float* wpe  = (const float*)d_in[5];
    const float* ln1w = (const float*)d_in[6];
    const float* ln1b = (const float*)d_in[7];
    const float* qkvw = (const float*)d_in[8];
    const float* qkvb = (const float*)d_in[9];
    const float* pw   = (const float*)d_in[10];
    const float* pb   = (const float*)d_in[11];
    const float* ln2w = (const float*)d_in[12];
    const float* ln2b = (const float*)d_in[13];
    const float* fcw  = (const float*)d_in[14];
    const float* fcb  = (const float*)d_in[15];
    const float* f2w  = (const float*)d_in[16];
    const float* f2b  = (const float*)d_in[17];
    const float* lnfw = (const float*)d_in[18];
    const float* lnfb = (const float*)d_in[19];
    const float* lmw  = (const float*)d_in[20];
    const float* tpw  = (const float*)d_in[21];
    float* out = (float*)d_out;

    const int n_qkvw = 3 * Cc * Cc, n_pw = Cc * Cc, n_fcw = 4 * Cc * Cc;

    // ---- workspace layout ----
    char* p = (char*)d_ws;
    float* x    = (float*)p;               p += (size_t)MTOT * Cc * 4;
    u16*   qkvB = (u16*)p;                 p += (size_t)MTOT * 3 * Cc * 2;
    u16*   VtB  = (u16*)p;                 p += (size_t)Bb * Hh * Dd * Tt * 2;
    u16*   hB   = (u16*)p;                 p += (size_t)MTOT * Cc * 2;   // packed
    u16*   yB   = (u16*)p;                 p += (size_t)MTOT * Cc * 2;
    u16*   mbB  = (u16*)p;                 p += (size_t)MTOT * 4 * Cc * 2;
    u16*   lmwB = (u16*)p;                 p += (size_t)Vv * Cc * 2;
    float* sbias= (float*)p;               p += (size_t)Ll * 3 * Cc * 4;
    char* wbase = p;

    size_t need_big = (size_t)(wbase - (char*)d_ws)
                    + ((size_t)Ll * (n_qkvw + n_pw + 2 * n_fcw)) * 2;
    bool big = ws_size >= need_big;

    u16 *wqA, *wpA, *wfA, *wf2A;
    if (big) {
        wqA  = (u16*)wbase;                wbase += (size_t)Ll * n_qkvw * 2;
        wpA  = (u16*)wbase;                wbase += (size_t)Ll * n_pw * 2;
        wfA  = (u16*)wbase;                wbase += (size_t)Ll * n_fcw * 2;
        wf2A = (u16*)wbase;
    } else {
        wqA  = (u16*)wbase;                wbase += (size_t)n_qkvw * 2;
        wpA  = (u16*)wbase;                wbase += (size_t)n_pw * 2;
        wfA  = (u16*)wbase;                wbase += (size_t)n_fcw * 2;
        wf2A = (u16*)wbase;
    }

    auto pack = [&](const float* src, u16* dst, size_t rows, int K,
                    int rowmod, int scaleLim) {
        int nk8 = (int)(rows * K / 8);
        convert_pack<<<(nk8 + 255) / 256, 256, 0, stream>>>(
            src, dst, nk8, K, rowmod, scaleLim);
    };

    pack(lmw, lmwB, Vv, Cc, 0, 0);
    {
        int nb = Ll * 3 * Cc;
        scale_qkvb<<<(nb + 255) / 256, 256, 0, stream>>>(qkvb, sbias, nb);
    }
    if (big) {
        pack(qkvw, wqA,  (size_t)Ll * 3 * Cc, Cc, 3 * Cc, Cc);
        pack(pw,   wpA,  (size_t)Ll * Cc,     Cc, 0, 0);
        pack(fcw,  wfA,  (size_t)Ll * 4 * Cc, Cc, 0, 0);
        pack(f2w,  wf2A, (size_t)Ll * Cc, 4 * Cc, 0, 0);
    }
    embed_kernel<<<MTOT, 256, 0, stream>>>(idx, ts, wte, freq, ph, wpe, x);

    for (int l = 0; l < Ll; ++l) {
        u16 *wqB, *wpB, *wfB, *wf2B;
        if (big) {
            wqB  = wqA  + (size_t)l * n_qkvw;
            wpB  = wpA  + (size_t)l * n_pw;
            wfB  = wfA  + (size_t)l * n_fcw;
            wf2B = wf2A + (size_t)l * n_fcw;
        } else {
            wqB = wqA; wpB = wpA; wfB = wfA; wf2B = wf2A;
            pack(qkvw + (size_t)l * n_qkvw, wqB, 3 * Cc, Cc, 3 * Cc, Cc);
            pack(pw   + (size_t)l * n_pw,   wpB, Cc,     Cc, 0, 0);
            pack(fcw  + (size_t)l * n_fcw,  wfB, 4 * Cc, Cc, 0, 0);
            pack(f2w  + (size_t)l * n_fcw,  wf2B, Cc, 4 * Cc, 0, 0);
        }

        ln_pack16<<<MTOT / 16, 256, 0, stream>>>(x, ln1w + l * Cc, ln1b + l * Cc, hB);
        gemm_nk64<3, 1, u16><<<dim3(64, 18), 256, 0, stream>>>(
            hB, wqB, sbias + (size_t)l * 3 * Cc, nullptr, qkvB, VtB, 3 * Cc, Cc);
        attn_mfma<<<dim3(Tt / 128, Bb * Hh), 512, 0, stream>>>(qkvB, VtB, yB);
        gemm_nk64<1, 0, float><<<dim3(64, 6), 256, 0, stream>>>(
            yB, wpB, pb + (size_t)l * Cc, x, x, nullptr, Cc, Cc);
        ln_pack16<<<MTOT / 16, 256, 0, stream>>>(x, ln2w + l * Cc, ln2b + l * Cc, hB);
        gemm_nk64<2, 1, u16><<<dim3(64, 24), 256, 0, stream>>>(
            hB, wfB, fcb + (size_t)l * 4 * Cc, nullptr, mbB, nullptr, 4 * Cc, Cc);
        gemm_nk64<1, 0, float><<<dim3(64, 6), 256, 0, stream>>>(
            mbB, wf2B, f2b + (size_t)l * Cc, x, x, nullptr, Cc, 4 * Cc);
    }

    ln_pack16<<<MTOT / 16, 256, 0, stream>>>(x, lnfw, lnfb, hB);
    gemm8p<0, float><<<dim3(16, 40), 512, 0, stream>>>(
        hB, lmwB, nullptr, nullptr, out, Vv, Cc);
    tpred_kernel<<<MTOT / 4, 256, 0, stream>>>(hB, tpw, out + (size_t)MTOT * Vv);
}

// Round 17
// 2453.710 us; speedup vs baseline: 1.0499x; 1.0499x over previous
//
#include <hip/hip_runtime.h>
#include <hip/hip_bf16.h>
#include <math.h>

#define Bb   4
#define Tt   1024
#define Cc   768
#define Hh   12
#define Dd   64
#define Ll   12
#define Vv   10000
#define WTEe 704
#define MTOT 4096   // B*T

// Q pre-scale: 1/sqrt(64) * log2(e)  (attention uses exp2)
#define QSCALE 0.18033688f

typedef __bf16 bf16x8 __attribute__((ext_vector_type(8)));
typedef float  f32x4  __attribute__((ext_vector_type(4)));
typedef unsigned short u16;

typedef const __attribute__((address_space(1))) void* gptr_t;
typedef __attribute__((address_space(3))) void* lptr_t;

__device__ inline void gload16(const void* g, void* l) {
    __builtin_amdgcn_global_load_lds((gptr_t)g, (lptr_t)l, 16, 0, 0);
}

__device__ inline u16 f2bf(float f) {
    unsigned int u = __float_as_uint(f);
    return (u16)((u + 0x7fffu + ((u >> 16) & 1u)) >> 16);   // RNE
}
__device__ inline float bf2f(u16 u) { return __uint_as_float(((unsigned)u) << 16); }

__device__ inline float gelu_f(float v) {
    float t = v * (0.797884561f + 0.0356774081f * v * v);
    float e = __expf(2.f * t);
    float th = 1.f - 2.f / (e + 1.f);
    return 0.5f * v * (1.f + th);
}

#if __has_builtin(__builtin_amdgcn_exp2f)
__device__ inline float fast_exp2(float x) { return __builtin_amdgcn_exp2f(x); }
#else
__device__ inline float fast_exp2(float x) { return exp2f(x); }
#endif

#define WAITVM(N)  asm volatile("s_waitcnt vmcnt(" #N ")" ::: "memory")
#define WAITLGKM0() asm volatile("s_waitcnt lgkmcnt(0)" ::: "memory")
#define SCHEDB()   __builtin_amdgcn_sched_barrier(0)
#define SBAR()     __builtin_amdgcn_s_barrier()

// ---------------------------------------------------------------------------
// Weight pack: f32 [Nall][K] row-major -> bf16 fragment blocks.
// ---------------------------------------------------------------------------
__global__ __launch_bounds__(256)
void convert_pack(const float* __restrict__ in, u16* __restrict__ out,
                  int nk8, int K, int rowmod, int scaleLim)
{
    int i = blockIdx.x * 256 + threadIdx.x;
    if (i >= nk8) return;
    int row = (i << 3) / K;
    int col = (i << 3) % K;
    float s = 1.f;
    if (rowmod && (row % rowmod) < scaleLim) s = QSCALE;
    float4 v0 = ((const float4*)in)[2 * i];
    float4 v1 = ((const float4*)in)[2 * i + 1];
    uint4 o;
    o.x = (unsigned)f2bf(v0.x * s) | ((unsigned)f2bf(v0.y * s) << 16);
    o.y = (unsigned)f2bf(v0.z * s) | ((unsigned)f2bf(v0.w * s) << 16);
    o.z = (unsigned)f2bf(v1.x * s) | ((unsigned)f2bf(v1.y * s) << 16);
    o.w = (unsigned)f2bf(v1.z * s) | ((unsigned)f2bf(v1.w * s) << 16);
    int tile = row >> 4, kt = col >> 5;
    int l = (row & 15) | (((col >> 3) & 3) << 4);
    size_t off = (((size_t)tile * (K >> 5) + kt) << 9) + l * 8;
    *(uint4*)(out + off) = o;
}

// qkv bias with Q prescale
__global__ __launch_bounds__(256)
void scale_qkvb(const float* __restrict__ in, float* __restrict__ out, int n)
{
    int i = blockIdx.x * 256 + threadIdx.x;
    if (i >= n) return;
    int col = i % (3 * Cc);
    out[i] = in[i] * (col < Cc ? QSCALE : 1.f);
}

// ---------------------------------------------------------------------------
// Embedding (f32 residual stream)
// ---------------------------------------------------------------------------
__global__ __launch_bounds__(256)
void embed_kernel(const int* __restrict__ idx, const float* __restrict__ ts,
                  const float* __restrict__ wte, const float* __restrict__ freq,
                  const float* __restrict__ ph, const float* __restrict__ wpe,
                  float* __restrict__ x)
{
    const int bt  = blockIdx.x;
    const int t   = bt & (Tt - 1);
    const int tok = idx[bt];
    const float tv = ts[bt];
#pragma unroll
    for (int j = 0; j < 3; ++j) {
        int c = threadIdx.x + (j << 8);
        float val;
        if (c < WTEe) val = wte[(size_t)tok * WTEe + c];
        else {
            int e = c - WTEe;
            val = cosf(tv * freq[e] + ph[e]);
        }
        x[(size_t)bt * Cc + c] = val + wpe[(size_t)t * Cc + c];
    }
}

// ---------------------------------------------------------------------------
// LayerNorm -> PACKED-A output. 16 rows per block (grid MTOT/16).
// ---------------------------------------------------------------------------
__global__ __launch_bounds__(256)
void ln_pack16(const float* __restrict__ x, const float* __restrict__ wt,
               const float* __restrict__ bs, u16* __restrict__ out)
{
    __shared__ float mus[16], rss[16];
    const int tid  = threadIdx.x;
    const int lane = tid & 63;
    const int w    = tid >> 6;
    const int tile = blockIdx.x;
    const int r0   = tile << 4;

#pragma unroll
    for (int rr = 0; rr < 4; ++rr) {
        const int row = r0 + w * 4 + rr;
        const float* xr = x + (size_t)row * Cc;
        float s = 0.f, s2 = 0.f;
#pragma unroll
        for (int j = 0; j < 12; ++j) {
            float v = xr[lane + (j << 6)];
            s += v; s2 += v * v;
        }
#pragma unroll
        for (int m = 32; m; m >>= 1) {
            s  += __shfl_xor(s, m);
            s2 += __shfl_xor(s2, m);
        }
        if (lane == 0) {
            float mu = s * (1.f / 768.f);
            float var = s2 * (1.f / 768.f) - mu * mu;
            mus[w * 4 + rr] = mu;
            rss[w * 4 + rr] = rsqrtf(var + 1e-5f);
        }
    }
    __syncthreads();

    u16* ob = out + ((size_t)tile * 24 << 9);
#pragma unroll
    for (int it = 0; it < 6; ++it) {
        int c   = tid + (it << 8);
        int kt  = c >> 6, l = c & 63;
        int row = l & 15, g = l >> 4;
        int col = kt * 32 + g * 8;
        float mu = mus[row], rs = rss[row];
        const float* xp = x + (size_t)(r0 + row) * Cc + col;
        float4 a = *(const float4*)xp;
        float4 bq = *(const float4*)(xp + 4);
        ushort o[8];
        o[0] = f2bf((a.x - mu) * rs * wt[col]     + bs[col]);
        o[1] = f2bf((a.y - mu) * rs * wt[col + 1] + bs[col + 1]);
        o[2] = f2bf((a.z - mu) * rs * wt[col + 2] + bs[col + 2]);
        o[3] = f2bf((a.w - mu) * rs * wt[col + 3] + bs[col + 3]);
        o[4] = f2bf((bq.x - mu) * rs * wt[col + 4] + bs[col + 4]);
        o[5] = f2bf((bq.y - mu) * rs * wt[col + 5] + bs[col + 5]);
        o[6] = f2bf((bq.z - mu) * rs * wt[col + 6] + bs[col + 6]);
        o[7] = f2bf((bq.w - mu) * rs * wt[col + 7] + bs[col + 7]);
        *(uint4*)(ob + ((size_t)kt << 9) + l * 8) = *(uint4*)o;
    }
}

// ---------------------------------------------------------------------------
// 128x128 bf16 GEMM, packed-B (+optionally packed-A): BK=32, 4 waves,
// triple-buffered 48 KB, counted vmcnt(4).  [r15 version — qkv/fc]
// EPI: 0 bias, 1 bias+f32 resid, 2 bias+GELU, 3 qkv (V cols -> vt[b,h,d,T])
// ---------------------------------------------------------------------------
__device__ inline void st_out(float* p, size_t o, float v) { p[o] = v; }
__device__ inline void st_out(u16*   p, size_t o, float v) { p[o] = f2bf(v); }

template<int EPI, int APK, typename OutT>
__global__ __launch_bounds__(256)
void gemm_bf16(const u16* __restrict__ A, const u16* __restrict__ Wp,
               const float* __restrict__ bias, const float* __restrict__ resid,
               OutT* __restrict__ out, u16* __restrict__ vt, int N, int K)
{
    __shared__ uint4 AF[3][8][64];
    __shared__ uint4 BF[3][8][64];
    const int tid  = threadIdx.x;
    const int lane = tid & 63;
    const int w    = tid >> 6;
    const int wr   = w >> 1, wc = w & 1;
    const int lq   = lane & 15, g = lane >> 4;
    const int m0   = blockIdx.x * 128, n0 = blockIdx.y * 128;
    const int KB   = K >> 5;

    const u16 *ap0, *ap1;
    if (APK) {
        ap0 = A + ((((size_t)(m0 >> 4) + 2 * w) * KB) << 9) + lane * 8;
        ap1 = ap0 + ((size_t)KB << 9);
    } else {
        ap0 = A + (size_t)(m0 + (2 * w) * 16 + lq) * K + g * 8;
        ap1 = ap0 + (size_t)16 * K;
    }

    int tn0 = (n0 >> 4) + 2 * w, tn1 = tn0 + 1;
    const int tmax = (N >> 4) - 1;
    tn0 = tn0 < tmax ? tn0 : tmax;
    tn1 = tn1 < tmax ? tn1 : tmax;
    const u16* bq0 = Wp + (((size_t)tn0 * KB) << 9) + lane * 8;
    const u16* bq1 = Wp + (((size_t)tn1 * KB) << 9) + lane * 8;

    f32x4 acc[4][4] = {};
    const int nk = KB;

#define GSTAGE(s, sl) do {                                               \
        if (APK) {                                                       \
            gload16(ap0 + ((size_t)(s) << 9), &AF[sl][2 * w][lane]);     \
            gload16(ap1 + ((size_t)(s) << 9), &AF[sl][2 * w + 1][lane]); \
        } else {                                                         \
            gload16(ap0 + ((s) << 5), &AF[sl][2 * w][lane]);             \
            gload16(ap1 + ((s) << 5), &AF[sl][2 * w + 1][lane]);         \
        }                                                                \
        gload16(bq0 + ((size_t)(s) << 9), &BF[sl][2 * w][lane]);         \
        gload16(bq1 + ((size_t)(s) << 9), &BF[sl][2 * w + 1][lane]); } while (0)

    GSTAGE(0, 0);
    GSTAGE(1, 1);
    WAITVM(4);
    SCHEDB();
    SBAR();
    SCHEDB();

    int sl = 0;
    for (int t = 0; t < nk; ++t) {
        int sl2 = sl + 2; if (sl2 >= 3) sl2 -= 3;
        if (t + 2 < nk) GSTAGE(t + 2, sl2);

        bf16x8 af[4], bfr[4];
#pragma unroll
        for (int mi = 0; mi < 4; ++mi)
            af[mi] = __builtin_bit_cast(bf16x8, AF[sl][wr * 4 + mi][lane]);
#pragma unroll
        for (int ni = 0; ni < 4; ++ni)
            bfr[ni] = __builtin_bit_cast(bf16x8, BF[sl][wc * 4 + ni][lane]);
        __builtin_amdgcn_s_setprio(1);
#pragma unroll
        for (int mi = 0; mi < 4; ++mi)
#pragma unroll
            for (int ni = 0; ni < 4; ++ni)
                acc[mi][ni] = __builtin_amdgcn_mfma_f32_16x16x32_bf16(
                    af[mi], bfr[ni], acc[mi][ni], 0, 0, 0);
        __builtin_amdgcn_s_setprio(0);

        if (t + 2 < nk) { WAITVM(4); }
        else           { WAITVM(0); }
        SCHEDB();
        SBAR();
        SCHEDB();
        sl = (sl + 1 == 3) ? 0 : sl + 1;
    }
#undef GSTAGE

    if (EPI == 3 && n0 >= 1536) {        // V block -> transposed vt[b,h,d,T]
#pragma unroll
        for (int mi = 0; mi < 4; ++mi)
#pragma unroll
            for (int ni = 0; ni < 4; ++ni) {
                int col = n0 + wc * 64 + ni * 16 + lq;
                int c2  = col - 1536;
                int hh  = c2 >> 6, dd = c2 & 63;
                int row = m0 + wr * 64 + mi * 16 + g * 4;
                int bb  = row >> 10, tr = row & 1023;
                float bv = bias[col];
                ushort4 o;
                o.x = f2bf(acc[mi][ni][0] + bv);
                o.y = f2bf(acc[mi][ni][1] + bv);
                o.z = f2bf(acc[mi][ni][2] + bv);
                o.w = f2bf(acc[mi][ni][3] + bv);
                *(ushort4*)&vt[(((size_t)bb * Hh + hh) * Dd + dd) * Tt + tr] = o;
            }
        return;
    }

#pragma unroll
    for (int mi = 0; mi < 4; ++mi)
#pragma unroll
        for (int ni = 0; ni < 4; ++ni) {
            int col = n0 + wc * 64 + ni * 16 + lq;
            if (col >= N) continue;
            int row = m0 + wr * 64 + mi * 16 + g * 4;
            float bv = bias ? bias[col] : 0.f;
#pragma unroll
            for (int q = 0; q < 4; ++q) {
                float v = acc[mi][ni][q] + bv;
                size_t o = (size_t)(row + q) * N + col;
                if (EPI == 1) v += resid[o];
                if (EPI == 2) v = gelu_f(v);
                st_out(out, o, v);
            }
        }
}

// ---------------------------------------------------------------------------
// 64x128 bf16 GEMM, BK=64, packed-B, row-major A (proj/fc2), SWAPPED
// operands: mfma(B,A) -> lane holds 4 consecutive n for one m -> float4
// epilogue stores + float4 resid/bias loads. Double-buffered 48 KB.
// ---------------------------------------------------------------------------
__global__ __launch_bounds__(256)
void gemm_n64(const u16* __restrict__ A, const u16* __restrict__ Wp,
              const float* __restrict__ bias, const float* __restrict__ resid,
              float* __restrict__ out, int N, int K)
{
    __shared__ uint4 AF[2][8][64];    // [buf][mt*2+slab]  16 KB
    __shared__ uint4 BF[2][16][64];   // [buf][nt*2+slab]  32 KB
    const int tid  = threadIdx.x;
    const int lane = tid & 63;
    const int w    = tid >> 6;
    const int wr   = w & 1, wc = w >> 1;
    const int lq   = lane & 15, g = lane >> 4;
    const int m0   = blockIdx.x * 64, n0 = blockIdx.y * 128;
    const int KB   = K >> 5;
    const int nk   = K >> 6;

    const u16* ap = A + (size_t)(m0 + w * 16 + lq) * K + g * 8;
    int tn0 = (n0 >> 4) + 2 * w, tn1 = tn0 + 1;
    const int tmax = (N >> 4) - 1;
    tn0 = tn0 < tmax ? tn0 : tmax;
    tn1 = tn1 < tmax ? tn1 : tmax;
    const u16* bq0 = Wp + (((size_t)tn0 * KB) << 9) + lane * 8;
    const u16* bq1 = Wp + (((size_t)tn1 * KB) << 9) + lane * 8;

    f32x4 acc[2][4] = {};

#define GSTAGE(t, bi) do {                                                 \
        gload16(ap + ((t) << 6),      &AF[bi][2 * w][lane]);               \
        gload16(ap + ((t) << 6) + 32, &AF[bi][2 * w + 1][lane]);           \
        gload16(bq0 + ((size_t)(2 * (t)) << 9),     &BF[bi][4 * w][lane]); \
        gload16(bq0 + ((size_t)(2 * (t) + 1) << 9), &BF[bi][4 * w + 1][lane]); \
        gload16(bq1 + ((size_t)(2 * (t)) << 9),     &BF[bi][4 * w + 2][lane]); \
        gload16(bq1 + ((size_t)(2 * (t) + 1) << 9), &BF[bi][4 * w + 3][lane]); } while (0)

    GSTAGE(0, 0);
    WAITVM(0);
    SCHEDB();
    SBAR();
    SCHEDB();

    for (int t = 0; t < nk; ++t) {
        const int buf = t & 1;
        if (t + 1 < nk) GSTAGE(t + 1, buf ^ 1);

#pragma unroll
        for (int s = 0; s < 2; ++s) {
            bf16x8 a0 = __builtin_bit_cast(bf16x8, AF[buf][(wr * 2) * 2 + s][lane]);
            bf16x8 a1 = __builtin_bit_cast(bf16x8, AF[buf][(wr * 2 + 1) * 2 + s][lane]);
            bf16x8 bb[4];
#pragma unroll
            for (int ni = 0; ni < 4; ++ni)
                bb[ni] = __builtin_bit_cast(bf16x8, BF[buf][(wc * 4 + ni) * 2 + s][lane]);
            __builtin_amdgcn_s_setprio(1);
#pragma unroll
            for (int ni = 0; ni < 4; ++ni) {
                acc[0][ni] = __builtin_amdgcn_mfma_f32_16x16x32_bf16(
                    bb[ni], a0, acc[0][ni], 0, 0, 0);
                acc[1][ni] = __builtin_amdgcn_mfma_f32_16x16x32_bf16(
                    bb[ni], a1, acc[1][ni], 0, 0, 0);
            }
            __builtin_amdgcn_s_setprio(0);
        }

        WAITVM(0);     // own 6 staged loads; issued a full phase earlier
        SCHEDB();
        SBAR();
        SCHEDB();
    }
#undef GSTAGE

    // swapped epilogue: lane (lq,g) holds n = n0+wc*64+ni*16+g*4..+3 of
    // row m = m0+(wr*2+mi)*16+lq  ->  one float4 store per fragment.
#pragma unroll
    for (int mi = 0; mi < 2; ++mi)
#pragma unroll
        for (int ni = 0; ni < 4; ++ni) {
            int m = m0 + (wr * 2 + mi) * 16 + lq;
            int n = n0 + wc * 64 + ni * 16 + (g << 2);
            float4 bv = *(const float4*)&bias[n];
            size_t o = (size_t)m * N + n;
            float4 rv = *(const float4*)&resid[o];
            float4 v;
            v.x = acc[mi][ni][0] + bv.x + rv.x;
            v.y = acc[mi][ni][1] + bv.y + rv.y;
            v.z = acc[mi][ni][2] + bv.z + rv.z;
            v.w = acc[mi][ni][3] + bv.w + rv.w;
            *(float4*)&out[o] = v;
        }
}

// ---------------------------------------------------------------------------
// 256x256 8-phase bf16 GEMM, packed-A + packed-B, SWAPPED operands —
// lm_head only. Epilogue: float4 stores (N-tail guarded).
// ---------------------------------------------------------------------------
__global__ __launch_bounds__(512, 2)
void gemm8p(const u16* __restrict__ Apk, const u16* __restrict__ Wp,
            float* __restrict__ out, int N, int K)
{
    __shared__ uint4 AF[2][16][2][64];
    __shared__ uint4 BF[2][16][2][64];
    const int tid  = threadIdx.x;
    const int lane = tid & 63;
    const int w    = tid >> 6;
    const int wr   = w >> 2, wc = w & 3;
    const int lq   = lane & 15, g = lane >> 4;
    const int m0   = blockIdx.x * 256, n0 = blockIdx.y * 256;
    const int KB   = K >> 5;

    const u16* aq0 = Apk + ((((size_t)(m0 >> 4) + 2 * w) * KB) << 9) + lane * 8;
    const u16* aq1 = aq0 + ((size_t)KB << 9);

    int tn0 = (n0 >> 4) + 2 * w, tn1 = tn0 + 1;
    const int tmax = (N >> 4) - 1;
    tn0 = tn0 < tmax ? tn0 : tmax;
    tn1 = tn1 < tmax ? tn1 : tmax;
    const u16* bq0 = Wp + (((size_t)tn0 * KB) << 9) + lane * 8;
    const u16* bq1 = Wp + (((size_t)tn1 * KB) << 9) + lane * 8;

    f32x4 acc[8][4] = {};
    const int nt = K >> 6;

    gload16(aq0,       &AF[0][2 * w][0][lane]);
    gload16(aq1,       &AF[0][2 * w + 1][0][lane]);
    gload16(bq0,       &BF[0][2 * w][0][lane]);
    gload16(bq1,       &BF[0][2 * w + 1][0][lane]);
    gload16(aq0 + 512, &AF[0][2 * w][1][lane]);
    gload16(aq1 + 512, &AF[0][2 * w + 1][1][lane]);
    gload16(bq0 + 512, &BF[0][2 * w][1][lane]);
    gload16(bq1 + 512, &BF[0][2 * w + 1][1][lane]);
    WAITVM(0);
    SCHEDB();
    SBAR();

    int buf = 0;
    for (int t = 0; t < nt; ++t) {
        const bool more = (t + 1 < nt);
        const size_t bb0 = (size_t)(2 * (t + 1)) << 9;
        bf16x8 a0[4], a1[4], b0[4];

#pragma unroll
        for (int i = 0; i < 4; ++i)
            a0[i] = __builtin_bit_cast(bf16x8, AF[buf][wr * 8 + i][0][lane]);
#pragma unroll
        for (int i = 0; i < 4; ++i)
            b0[i] = __builtin_bit_cast(bf16x8, BF[buf][wc * 4 + i][0][lane]);
        if (more) {
            gload16(aq0 + bb0, &AF[buf ^ 1][2 * w][0][lane]);
            gload16(aq1 + bb0, &AF[buf ^ 1][2 * w + 1][0][lane]);
        }
        SCHEDB();
        SBAR();
        WAITLGKM0();
        SCHEDB();
        __builtin_amdgcn_s_setprio(1);
#pragma unroll
        for (int mi = 0; mi < 4; ++mi)
#pragma unroll
            for (int ni = 0; ni < 4; ++ni)
                acc[mi][ni] = __builtin_amdgcn_mfma_f32_16x16x32_bf16(
                    b0[ni], a0[mi], acc[mi][ni], 0, 0, 0);
        __builtin_amdgcn_s_setprio(0);
        SBAR();

#pragma unroll
        for (int i = 0; i < 4; ++i)
            a1[i] = __builtin_bit_cast(bf16x8, AF[buf][wr * 8 + 4 + i][0][lane]);
        if (more) {
            gload16(bq0 + bb0, &BF[buf ^ 1][2 * w][0][lane]);
            gload16(bq1 + bb0, &BF[buf ^ 1][2 * w + 1][0][lane]);
        }
        SCHEDB();
        SBAR();
        WAITLGKM0();
        SCHEDB();
        __builtin_amdgcn_s_setprio(1);
#pragma unroll
        for (int mi = 0; mi < 4; ++mi)
#pragma unroll
            for (int ni = 0; ni < 4; ++ni)
                acc[4 + mi][ni] = __builtin_amdgcn_mfma_f32_16x16x32_bf16(
                    b0[ni], a1[mi], acc[4 + mi][ni], 0, 0, 0);
        __builtin_amdgcn_s_setprio(0);
        if (more) { WAITVM(4); } else { WAITVM(0); }
        SCHEDB();
        SBAR();

#pragma unroll
        for (int i = 0; i < 4; ++i)
            a0[i] = __builtin_bit_cast(bf16x8, AF[buf][wr * 8 + i][1][lane]);
#pragma unroll
        for (int i = 0; i < 4; ++i)
            b0[i] = __builtin_bit_cast(bf16x8, BF[buf][wc * 4 + i][1][lane]);
        if (more) {
            gload16(aq0 + bb0 + 512, &AF[buf ^ 1][2 * w][1][lane]);
            gload16(aq1 + bb0 + 512, &AF[buf ^ 1][2 * w + 1][1][lane]);
        }
        SCHEDB();
        SBAR();
        WAITLGKM0();
        SCHEDB();
        __builtin_amdgcn_s_setprio(1);
#pragma unroll
        for (int mi = 0; mi < 4; ++mi)
#pragma unroll
            for (int ni = 0; ni < 4; ++ni)
                acc[mi][ni] = __builtin_amdgcn_mfma_f32_16x16x32_bf16(
                    b0[ni], a0[mi], acc[mi][ni], 0, 0, 0);
        __builtin_amdgcn_s_setprio(0);
        SBAR();

#pragma unroll
        for (int i = 0; i < 4; ++i)
            a1[i] = __builtin_bit_cast(bf16x8, AF[buf][wr * 8 + 4 + i][1][lane]);
        if (more) {
            gload16(bq0 + bb0 + 512, &BF[buf ^ 1][2 * w][1][lane]);
            gload16(bq1 + bb0 + 512, &BF[buf ^ 1][2 * w + 1][1][lane]);
        }
        SCHEDB();
        SBAR();
        WAITLGKM0();
        SCHEDB();
        __builtin_amdgcn_s_setprio(1);
#pragma unroll
        for (int mi = 0; mi < 4; ++mi)
#pragma unroll
            for (int ni = 0; ni < 4; ++ni)
                acc[4 + mi][ni] = __builtin_amdgcn_mfma_f32_16x16x32_bf16(
                    b0[ni], a1[mi], acc[4 + mi][ni], 0, 0, 0);
        __builtin_amdgcn_s_setprio(0);
        if (more) { WAITVM(4); } else { WAITVM(0); }
        SCHEDB();
        SBAR();

        buf ^= 1;
    }

    // swapped epilogue: lane (lq,g) holds n = n0+wc*64+ni*16+g*4..+3 of
    // row m = m0+wr*128+mi*16+lq -> float4 store (tail-guarded, N=10000).
#pragma unroll
    for (int mi = 0; mi < 8; ++mi)
#pragma unroll
        for (int ni = 0; ni < 4; ++ni) {
            int m = m0 + wr * 128 + mi * 16 + lq;
            int n = n0 + wc * 64 + ni * 16 + (g << 2);
            size_t o = (size_t)m * N + n;
            if (n + 3 < N) {
                float4 v;
                v.x = acc[mi][ni][0]; v.y = acc[mi][ni][1];
                v.z = acc[mi][ni][2]; v.w = acc[mi][ni][3];
                *(float4*)&out[o] = v;
            } else {
#pragma unroll
                for (int q = 0; q < 4; ++q)
                    if (n + q < N) out[o + q] = acc[mi][ni][q];
            }
        }
}

// ---------------------------------------------------------------------------
// MFMA flash attention, QBLK=128 / 8 waves, swapped QK^T (r13/r15 version).
// ---------------------------------------------------------------------------
__global__ __launch_bounds__(512)
void attn_mfma(const u16* __restrict__ qkv, const u16* __restrict__ vt,
               u16* __restrict__ y)
{
    __shared__ uint4 KF[2][4][2][64];
    __shared__ uint4 VF[2][4][2][64];

    const int tid  = threadIdx.x;
    const int lane = tid & 63;
    const int w    = tid >> 6;
    const int lq   = lane & 15, g = lane >> 4;
    const int m    = gridDim.x - 1 - blockIdx.x;   // heavy blocks first
    const int bh   = blockIdx.y;
    const int b    = bh / Hh, h = bh % Hh;
    const int wq0  = m * 128 + w * 16;
    const size_t base = (size_t)b * Tt * (3 * Cc);

    const u16* qrow = qkv + base + (size_t)(wq0 + lq) * (3 * Cc) + h * Dd;
    bf16x8 qf0 = __builtin_bit_cast(bf16x8, *(const uint4*)(qrow + g * 8));
    bf16x8 qf1 = __builtin_bit_cast(bf16x8, *(const uint4*)(qrow + 32 + g * 8));

    f32x4 yac[4] = {};
    float lrun = 0.f;

    const int wm = w & 3;
    const u16* kbase = qkv + base + Cc + h * Dd + (size_t)(wm * 16 + lq) * (3 * Cc) + g * 8;
    const u16* vbase = vt + ((size_t)bh * Dd + wm * 16 + lq) * Tt + g * 8;

#define STAGE(c, bi)  do {                                              \
        if (w < 4) {                                                    \
            const u16* kp = kbase + (size_t)(c) * 64 * (3 * Cc);        \
            gload16(kp,      &KF[bi][wm][0][lane]);                     \
            gload16(kp + 32, &KF[bi][wm][1][lane]);                     \
        } else {                                                        \
            const u16* vp = vbase + (c) * 64;                           \
            gload16(vp,      &VF[bi][wm][0][lane]);                     \
            gload16(vp + 32, &VF[bi][wm][1][lane]);                     \
        }                                                               \
    } while (0)

    const int nch = 2 * m + 2;
    STAGE(0, 0);
    WAITVM(0);
    SCHEDB();
    SBAR();

    const int srcb = lq + ((g & 1) << 5);

    int buf = 0;
    for (int c = 0; c < nch; ++c) {
        if (c + 1 < nch) STAGE(c + 1, buf ^ 1);

        f32x4 sc[4] = {};
        __builtin_amdgcn_s_setprio(1);
#pragma unroll
        for (int nt = 0; nt < 4; ++nt) {
            bf16x8 k0 = __builtin_bit_cast(bf16x8, KF[buf][nt][0][lane]);
            bf16x8 k1 = __builtin_bit_cast(bf16x8, KF[buf][nt][1][lane]);
            sc[nt] = __builtin_amdgcn_mfma_f32_16x16x32_bf16(k0, qf0, sc[nt], 0, 0, 0);
            sc[nt] = __builtin_amdgcn_mfma_f32_16x16x32_bf16(k1, qf1, sc[nt], 0, 0, 0);
        }
        __builtin_amdgcn_s_setprio(0);

        const int s0 = c * 64;
        if (s0 + 63 > wq0) {
            const int qg = wq0 + lq;
#pragma unroll
            for (int nt = 0; nt < 4; ++nt) {
                const int kb = s0 + nt * 16 + (g << 2);
#pragma unroll
                for (int j = 0; j < 4; ++j)
                    if (kb + j > qg) sc[nt][j] = -1e30f;
            }
        }

        float ls = 0.f;
#pragma unroll
        for (int nt = 0; nt < 4; ++nt)
#pragma unroll
            for (int j = 0; j < 4; ++j) {
                float p = fast_exp2(sc[nt][j]);
                sc[nt][j] = p;
                ls += p;
            }
        ls += __shfl_xor(ls, 16);
        ls += __shfl_xor(ls, 32);
        lrun += ls;

        unsigned pk[4][2];
#pragma unroll
        for (int nt = 0; nt < 4; ++nt) {
            unsigned u0 = __float_as_uint(sc[nt][0]);
            unsigned u1 = __float_as_uint(sc[nt][1]);
            unsigned u2 = __float_as_uint(sc[nt][2]);
            unsigned u3 = __float_as_uint(sc[nt][3]);
            pk[nt][0] = (u0 >> 16) | (u1 & 0xffff0000u);
            pk[nt][1] = (u2 >> 16) | (u3 & 0xffff0000u);
        }

        unsigned pa0[4], pa1[4];
#pragma unroll
        for (int m2 = 0; m2 < 4; ++m2) {
            int hsel = m2 & 1;
            int src  = srcb + ((m2 >> 1) << 4);
            unsigned lo0 = __shfl(pk[0][hsel], src);
            unsigned hi0 = __shfl(pk[1][hsel], src);
            unsigned lo1 = __shfl(pk[2][hsel], src);
            unsigned hi1 = __shfl(pk[3][hsel], src);
            pa0[m2] = (g >> 1) ? hi0 : lo0;
            pa1[m2] = (g >> 1) ? hi1 : lo1;
        }
        uint4 A0 = make_uint4(pa0[0], pa0[1], pa0[2], pa0[3]);
        uint4 A1 = make_uint4(pa1[0], pa1[1], pa1[2], pa1[3]);
        bf16x8 pA0 = __builtin_bit_cast(bf16x8, A0);
        bf16x8 pA1 = __builtin_bit_cast(bf16x8, A1);

        __builtin_amdgcn_s_setprio(1);
#pragma unroll
        for (int dt = 0; dt < 4; ++dt) {
            bf16x8 vb0 = __builtin_bit_cast(bf16x8, VF[buf][dt][0][lane]);
            bf16x8 vb1 = __builtin_bit_cast(bf16x8, VF[buf][dt][1][lane]);
            yac[dt] = __builtin_amdgcn_mfma_f32_16x16x32_bf16(pA0, vb0, yac[dt], 0, 0, 0);
            yac[dt] = __builtin_amdgcn_mfma_f32_16x16x32_bf16(pA1, vb1, yac[dt], 0, 0, 0);
        }
        __builtin_amdgcn_s_setprio(0);

        if (c + 1 < nch) { WAITVM(0); }
        SCHEDB();
        SBAR();
        buf ^= 1;
    }
#undef STAGE

    f32x4 rl;
#pragma unroll
    for (int j = 0; j < 4; ++j)
        rl[j] = 1.0f / __shfl(lrun, (g << 2) + j);
#pragma unroll
    for (int dt = 0; dt < 4; ++dt)
#pragma unroll
        for (int j = 0; j < 4; ++j)
            y[(size_t)(b * Tt + wq0 + (g << 2) + j) * Cc + h * Dd + dt * 16 + lq]
                = f2bf(yac[dt][j] * rl[j]);
}

// ---------------------------------------------------------------------------
// tpred (packed-A hB): out[row] = dot(h[row], tp_w)
// ---------------------------------------------------------------------------
__global__ __launch_bounds__(256)
void tpred_kernel(const u16* __restrict__ hp, const float* __restrict__ tp,
                  float* __restrict__ out)
{
    const int row  = blockIdx.x * 4 + (threadIdx.x >> 6);
    const int lane = threadIdx.x & 63;
    const int tile = row >> 4, r15 = row & 15;
    const u16* tb = hp + ((size_t)tile * 24 << 9);
    float s = 0.f;
#pragma unroll
    for (int j = 0; j < 12; ++j) {
        int col = lane + (j << 6);
        int kt = col >> 5, g = (col >> 3) & 3, e = col & 7;
        s += bf2f(tb[((size_t)kt << 9) + (r15 | (g << 4)) * 8 + e]) * tp[col];
    }
#pragma unroll
    for (int m = 32; m; m >>= 1) s += __shfl_xor(s, m);
    if (lane == 0) out[row] = s;
}

// ---------------------------------------------------------------------------
extern "C" void kernel_launch(void* const* d_in, const int* in_sizes, int n_in,
                              void* d_out, int out_size, void* d_ws, size_t ws_size,
                              hipStream_t stream)
{
    const int*   idx  = (const int*)d_in[0];
    const float* ts   = (const float*)d_in[1];
    const float* wte  = (const float*)d_in[2];
    const float* freq = (const float*)d_in[3];
    const float* ph   = (const float*)d_in[4];
    const float* wpe  = (const float*)d_in[5];
    const float* ln1w = (const float*)d_in[6];
    const float* ln1b = (const float*)d_in[7];
    const float* qkvw = (const float*)d_in[8];
    const float* qkvb = (const float*)d_in[9];
    const float* pw   = (const float*)d_in[10];
    const float* pb   = (const float*)d_in[11];
    const float* ln2w = (const float*)d_in[12];
    const float* ln2b = (const float*)d_in[13];
    const float* fcw  = (const float*)d_in[14];
    const float* fcb  = (const float*)d_in[15];
    const float* f2w  = (const float*)d_in[16];
    const float* f2b  = (const float*)d_in[17];
    const float* lnfw = (const float*)d_in[18];
    const float* lnfb = (const float*)d_in[19];
    const float* lmw  = (const float*)d_in[20];
    const float* tpw  = (const float*)d_in[21];
    float* out = (float*)d_out;

    const int n_qkvw = 3 * Cc * Cc, n_pw = Cc * Cc, n_fcw = 4 * Cc * Cc;

    // ---- workspace layout ----
    char* p = (char*)d_ws;
    float* x    = (float*)p;               p += (size_t)MTOT * Cc * 4;
    u16*   qkvB = (u16*)p;                 p += (size_t)MTOT * 3 * Cc * 2;
    u16*   VtB  = (u16*)p;                 p += (size_t)Bb * Hh * Dd * Tt * 2;
    u16*   hB   = (u16*)p;                 p += (size_t)MTOT * Cc * 2;   // packed
    u16*   yB   = (u16*)p;                 p += (size_t)MTOT * Cc * 2;
    u16*   mbB  = (u16*)p;                 p += (size_t)MTOT * 4 * Cc * 2;
    u16*   lmwB = (u16*)p;                 p += (size_t)Vv * Cc * 2;
    float* sbias= (float*)p;               p += (size_t)Ll * 3 * Cc * 4;
    char* wbase = p;

    size_t need_big = (size_t)(wbase - (char*)d_ws)
                    + ((size_t)Ll * (n_qkvw + n_pw + 2 * n_fcw)) * 2;
    bool big = ws_size >= need_big;

    u16 *wqA, *wpA, *wfA, *wf2A;
    if (big) {
        wqA  = (u16*)wbase;                wbase += (size_t)Ll * n_qkvw * 2;
        wpA  = (u16*)wbase;                wbase += (size_t)Ll * n_pw * 2;
        wfA  = (u16*)wbase;                wbase += (size_t)Ll * n_fcw * 2;
        wf2A = (u16*)wbase;
    } else {
        wqA  = (u16*)wbase;                wbase += (size_t)n_qkvw * 2;
        wpA  = (u16*)wbase;                wbase += (size_t)n_pw * 2;
        wfA  = (u16*)wbase;                wbase += (size_t)n_fcw * 2;
        wf2A = (u16*)wbase;
    }

    auto pack = [&](const float* src, u16* dst, size_t rows, int K,
                    int rowmod, int scaleLim) {
        int nk8 = (int)(rows * K / 8);
        convert_pack<<<(nk8 + 255) / 256, 256, 0, stream>>>(
            src, dst, nk8, K, rowmod, scaleLim);
    };

    pack(lmw, lmwB, Vv, Cc, 0, 0);
    {
        int nb = Ll * 3 * Cc;
        scale_qkvb<<<(nb + 255) / 256, 256, 0, stream>>>(qkvb, sbias, nb);
    }
    if (big) {
        pack(qkvw, wqA,  (size_t)Ll * 3 * Cc, Cc, 3 * Cc, Cc);
        pack(pw,   wpA,  (size_t)Ll * Cc,     Cc, 0, 0);
        pack(fcw,  wfA,  (size_t)Ll * 4 * Cc, Cc, 0, 0);
        pack(f2w,  wf2A, (size_t)Ll * Cc, 4 * Cc, 0, 0);
    }
    embed_kernel<<<MTOT, 256, 0, stream>>>(idx, ts, wte, freq, ph, wpe, x);

    for (int l = 0; l < Ll; ++l) {
        u16 *wqB, *wpB, *wfB, *wf2B;
        if (big) {
            wqB  = wqA  + (size_t)l * n_qkvw;
            wpB  = wpA  + (size_t)l * n_pw;
            wfB  = wfA  + (size_t)l * n_fcw;
            wf2B = wf2A + (size_t)l * n_fcw;
        } else {
            wqB = wqA; wpB = wpA; wfB = wfA; wf2B = wf2A;
            pack(qkvw + (size_t)l * n_qkvw, wqB, 3 * Cc, Cc, 3 * Cc, Cc);
            pack(pw   + (size_t)l * n_pw,   wpB, Cc,     Cc, 0, 0);
            pack(fcw  + (size_t)l * n_fcw,  wfB, 4 * Cc, Cc, 0, 0);
            pack(f2w  + (size_t)l * n_fcw,  wf2B, Cc, 4 * Cc, 0, 0);
        }

        ln_pack16<<<MTOT / 16, 256, 0, stream>>>(x, ln1w + l * Cc, ln1b + l * Cc, hB);
        gemm_bf16<3, 1, u16><<<dim3(32, 18), 256, 0, stream>>>(
            hB, wqB, sbias + (size_t)l * 3 * Cc, nullptr, qkvB, VtB, 3 * Cc, Cc);
        attn_mfma<<<dim3(Tt / 128, Bb * Hh), 512, 0, stream>>>(qkvB, VtB, yB);
        gemm_n64<<<dim3(64, 6), 256, 0, stream>>>(
            yB, wpB, pb + (size_t)l * Cc, x, x, Cc, Cc);
        ln_pack16<<<MTOT / 16, 256, 0, stream>>>(x, ln2w + l * Cc, ln2b + l * Cc, hB);
        gemm_bf16<2, 1, u16><<<dim3(32, 24), 256, 0, stream>>>(
            hB, wfB, fcb + (size_t)l * 4 * Cc, nullptr, mbB, nullptr, 4 * Cc, Cc);
        gemm_n64<<<dim3(64, 6), 256, 0, stream>>>(
            mbB, wf2B, f2b + (size_t)l * Cc, x, x, Cc, 4 * Cc);
    }

    ln_pack16<<<MTOT / 16, 256, 0, stream>>>(x, lnfw, lnfb, hB);
    gemm8p<<<dim3(16, 40), 512, 0, stream>>>(hB, lmwB, out, Vv, Cc);
    tpred_kernel<<<MTOT / 4, 256, 0, stream>>>(hB, tpw, out + (size_t)MTOT * Vv);
}

// Round 18
// 2432.410 us; speedup vs baseline: 1.0591x; 1.0088x over previous
//
#include <hip/hip_runtime.h>
#include <hip/hip_bf16.h>
#include <math.h>

#define Bb   4
#define Tt   1024
#define Cc   768
#define Hh   12
#define Dd   64
#define Ll   12
#define Vv   10000
#define WTEe 704
#define MTOT 4096   // B*T

// Q pre-scale: 1/sqrt(64) * log2(e)  (attention uses exp2)
#define QSCALE 0.18033688f

typedef __bf16 bf16x8 __attribute__((ext_vector_type(8)));
typedef float  f32x4  __attribute__((ext_vector_type(4)));
typedef unsigned short u16;

typedef const __attribute__((address_space(1))) void* gptr_t;
typedef __attribute__((address_space(3))) void* lptr_t;

__device__ inline void gload16(const void* g, void* l) {
    __builtin_amdgcn_global_load_lds((gptr_t)g, (lptr_t)l, 16, 0, 0);
}

__device__ inline u16 f2bf(float f) {
    unsigned int u = __float_as_uint(f);
    return (u16)((u + 0x7fffu + ((u >> 16) & 1u)) >> 16);   // RNE
}
__device__ inline float bf2f(u16 u) { return __uint_as_float(((unsigned)u) << 16); }

__device__ inline float gelu_f(float v) {
    float t = v * (0.797884561f + 0.0356774081f * v * v);
    float e = __expf(2.f * t);
    float th = 1.f - 2.f / (e + 1.f);
    return 0.5f * v * (1.f + th);
}

#if __has_builtin(__builtin_amdgcn_exp2f)
__device__ inline float fast_exp2(float x) { return __builtin_amdgcn_exp2f(x); }
#else
__device__ inline float fast_exp2(float x) { return exp2f(x); }
#endif

#define WAITVM(N)  asm volatile("s_waitcnt vmcnt(" #N ")" ::: "memory")
#define WAITLGKM0() asm volatile("s_waitcnt lgkmcnt(0)" ::: "memory")
#define SCHEDB()   __builtin_amdgcn_sched_barrier(0)
#define SBAR()     __builtin_amdgcn_s_barrier()

// ---------------------------------------------------------------------------
// Weight pack: f32 [Nall][K] row-major -> bf16 fragment blocks.
// ---------------------------------------------------------------------------
__global__ __launch_bounds__(256)
void convert_pack(const float* __restrict__ in, u16* __restrict__ out,
                  int nk8, int K, int rowmod, int scaleLim)
{
    int i = blockIdx.x * 256 + threadIdx.x;
    if (i >= nk8) return;
    int row = (i << 3) / K;
    int col = (i << 3) % K;
    float s = 1.f;
    if (rowmod && (row % rowmod) < scaleLim) s = QSCALE;
    float4 v0 = ((const float4*)in)[2 * i];
    float4 v1 = ((const float4*)in)[2 * i + 1];
    uint4 o;
    o.x = (unsigned)f2bf(v0.x * s) | ((unsigned)f2bf(v0.y * s) << 16);
    o.y = (unsigned)f2bf(v0.z * s) | ((unsigned)f2bf(v0.w * s) << 16);
    o.z = (unsigned)f2bf(v1.x * s) | ((unsigned)f2bf(v1.y * s) << 16);
    o.w = (unsigned)f2bf(v1.z * s) | ((unsigned)f2bf(v1.w * s) << 16);
    int tile = row >> 4, kt = col >> 5;
    int l = (row & 15) | (((col >> 3) & 3) << 4);
    size_t off = (((size_t)tile * (K >> 5) + kt) << 9) + l * 8;
    *(uint4*)(out + off) = o;
}

// qkv bias with Q prescale
__global__ __launch_bounds__(256)
void scale_qkvb(const float* __restrict__ in, float* __restrict__ out, int n)
{
    int i = blockIdx.x * 256 + threadIdx.x;
    if (i >= n) return;
    int col = i % (3 * Cc);
    out[i] = in[i] * (col < Cc ? QSCALE : 1.f);
}

// ---------------------------------------------------------------------------
// Embedding (f32 residual stream)
// ---------------------------------------------------------------------------
__global__ __launch_bounds__(256)
void embed_kernel(const int* __restrict__ idx, const float* __restrict__ ts,
                  const float* __restrict__ wte, const float* __restrict__ freq,
                  const float* __restrict__ ph, const float* __restrict__ wpe,
                  float* __restrict__ x)
{
    const int bt  = blockIdx.x;
    const int t   = bt & (Tt - 1);
    const int tok = idx[bt];
    const float tv = ts[bt];
#pragma unroll
    for (int j = 0; j < 3; ++j) {
        int c = threadIdx.x + (j << 8);
        float val;
        if (c < WTEe) val = wte[(size_t)tok * WTEe + c];
        else {
            int e = c - WTEe;
            val = cosf(tv * freq[e] + ph[e]);
        }
        x[(size_t)bt * Cc + c] = val + wpe[(size_t)t * Cc + c];
    }
}

// ---------------------------------------------------------------------------
// SINGLE-PASS LayerNorm -> PACKED-A output. 16 rows per block.
// Thread (tid) owns row = tid&15, g = (tid>>4)&3, kt = (tid>>6)+4*it:
// loads its 48 elements ONCE as 12 float4 (wave = 16 rows x 128B runs),
// per-thread s/s2, LDS cross-wave reduce (16 partials per row), normalize
// from registers, packed uint4 stores (fully coalesced).
// ---------------------------------------------------------------------------
__global__ __launch_bounds__(256)
void ln_pack16(const float* __restrict__ x, const float* __restrict__ wt,
               const float* __restrict__ bs, u16* __restrict__ out)
{
    __shared__ float ps[256], ps2[256];
    const int tid  = threadIdx.x;
    const int tile = blockIdx.x;
    const int r0   = tile << 4;
    const int row  = tid & 15;
    const int g    = (tid >> 4) & 3;
    const int kt0  = tid >> 6;

    const float* xr = x + (size_t)(r0 + row) * Cc;
    float4 va[6], vb[6];
    float s = 0.f, s2 = 0.f;
#pragma unroll
    for (int it = 0; it < 6; ++it) {
        int col = (kt0 + 4 * it) * 32 + g * 8;
        va[it] = *(const float4*)(xr + col);
        vb[it] = *(const float4*)(xr + col + 4);
        s  += va[it].x + va[it].y + va[it].z + va[it].w
            + vb[it].x + vb[it].y + vb[it].z + vb[it].w;
        s2 += va[it].x * va[it].x + va[it].y * va[it].y
            + va[it].z * va[it].z + va[it].w * va[it].w
            + vb[it].x * vb[it].x + vb[it].y * vb[it].y
            + vb[it].z * vb[it].z + vb[it].w * vb[it].w;
    }
    ps[tid] = s;
    ps2[tid] = s2;
    __syncthreads();

    float st = 0.f, st2 = 0.f;
#pragma unroll
    for (int j = 0; j < 16; ++j) {
        st  += ps[row + 16 * j];
        st2 += ps2[row + 16 * j];
    }
    float mu = st * (1.f / 768.f);
    float var = st2 * (1.f / 768.f) - mu * mu;
    float rs = rsqrtf(var + 1e-5f);

    u16* ob = out + ((size_t)tile * 24 << 9);
    const int l = tid & 63;
#pragma unroll
    for (int it = 0; it < 6; ++it) {
        int kt  = kt0 + 4 * it;
        int col = kt * 32 + g * 8;
        ushort o[8];
        o[0] = f2bf((va[it].x - mu) * rs * wt[col]     + bs[col]);
        o[1] = f2bf((va[it].y - mu) * rs * wt[col + 1] + bs[col + 1]);
        o[2] = f2bf((va[it].z - mu) * rs * wt[col + 2] + bs[col + 2]);
        o[3] = f2bf((va[it].w - mu) * rs * wt[col + 3] + bs[col + 3]);
        o[4] = f2bf((vb[it].x - mu) * rs * wt[col + 4] + bs[col + 4]);
        o[5] = f2bf((vb[it].y - mu) * rs * wt[col + 5] + bs[col + 5]);
        o[6] = f2bf((vb[it].z - mu) * rs * wt[col + 6] + bs[col + 6]);
        o[7] = f2bf((vb[it].w - mu) * rs * wt[col + 7] + bs[col + 7]);
        *(uint4*)(ob + ((size_t)kt << 9) + l * 8) = *(uint4*)o;
    }
}

// ---------------------------------------------------------------------------
// 128x128 bf16 GEMM, packed-B (+optionally packed-A): BK=32, 4 waves,
// triple-buffered 48 KB, counted vmcnt(4).  [qkv/fc]
// EPI: 0 bias, 1 bias+f32 resid, 2 bias+GELU, 3 qkv (V cols -> vt[b,h,d,T])
// ---------------------------------------------------------------------------
__device__ inline void st_out(float* p, size_t o, float v) { p[o] = v; }
__device__ inline void st_out(u16*   p, size_t o, float v) { p[o] = f2bf(v); }

template<int EPI, int APK, typename OutT>
__global__ __launch_bounds__(256)
void gemm_bf16(const u16* __restrict__ A, const u16* __restrict__ Wp,
               const float* __restrict__ bias, const float* __restrict__ resid,
               OutT* __restrict__ out, u16* __restrict__ vt, int N, int K)
{
    __shared__ uint4 AF[3][8][64];
    __shared__ uint4 BF[3][8][64];
    const int tid  = threadIdx.x;
    const int lane = tid & 63;
    const int w    = tid >> 6;
    const int wr   = w >> 1, wc = w & 1;
    const int lq   = lane & 15, g = lane >> 4;
    const int m0   = blockIdx.x * 128, n0 = blockIdx.y * 128;
    const int KB   = K >> 5;

    const u16 *ap0, *ap1;
    if (APK) {
        ap0 = A + ((((size_t)(m0 >> 4) + 2 * w) * KB) << 9) + lane * 8;
        ap1 = ap0 + ((size_t)KB << 9);
    } else {
        ap0 = A + (size_t)(m0 + (2 * w) * 16 + lq) * K + g * 8;
        ap1 = ap0 + (size_t)16 * K;
    }

    int tn0 = (n0 >> 4) + 2 * w, tn1 = tn0 + 1;
    const int tmax = (N >> 4) - 1;
    tn0 = tn0 < tmax ? tn0 : tmax;
    tn1 = tn1 < tmax ? tn1 : tmax;
    const u16* bq0 = Wp + (((size_t)tn0 * KB) << 9) + lane * 8;
    const u16* bq1 = Wp + (((size_t)tn1 * KB) << 9) + lane * 8;

    f32x4 acc[4][4] = {};
    const int nk = KB;

#define GSTAGE(s, sl) do {                                               \
        if (APK) {                                                       \
            gload16(ap0 + ((size_t)(s) << 9), &AF[sl][2 * w][lane]);     \
            gload16(ap1 + ((size_t)(s) << 9), &AF[sl][2 * w + 1][lane]); \
        } else {                                                         \
            gload16(ap0 + ((s) << 5), &AF[sl][2 * w][lane]);             \
            gload16(ap1 + ((s) << 5), &AF[sl][2 * w + 1][lane]);         \
        }                                                                \
        gload16(bq0 + ((size_t)(s) << 9), &BF[sl][2 * w][lane]);         \
        gload16(bq1 + ((size_t)(s) << 9), &BF[sl][2 * w + 1][lane]); } while (0)

    GSTAGE(0, 0);
    GSTAGE(1, 1);
    WAITVM(4);
    SCHEDB();
    SBAR();
    SCHEDB();

    int sl = 0;
    for (int t = 0; t < nk; ++t) {
        int sl2 = sl + 2; if (sl2 >= 3) sl2 -= 3;
        if (t + 2 < nk) GSTAGE(t + 2, sl2);

        bf16x8 af[4], bfr[4];
#pragma unroll
        for (int mi = 0; mi < 4; ++mi)
            af[mi] = __builtin_bit_cast(bf16x8, AF[sl][wr * 4 + mi][lane]);
#pragma unroll
        for (int ni = 0; ni < 4; ++ni)
            bfr[ni] = __builtin_bit_cast(bf16x8, BF[sl][wc * 4 + ni][lane]);
        __builtin_amdgcn_s_setprio(1);
#pragma unroll
        for (int mi = 0; mi < 4; ++mi)
#pragma unroll
            for (int ni = 0; ni < 4; ++ni)
                acc[mi][ni] = __builtin_amdgcn_mfma_f32_16x16x32_bf16(
                    af[mi], bfr[ni], acc[mi][ni], 0, 0, 0);
        __builtin_amdgcn_s_setprio(0);

        if (t + 2 < nk) { WAITVM(4); }
        else           { WAITVM(0); }
        SCHEDB();
        SBAR();
        SCHEDB();
        sl = (sl + 1 == 3) ? 0 : sl + 1;
    }
#undef GSTAGE

    if (EPI == 3 && n0 >= 1536) {        // V block -> transposed vt[b,h,d,T]
#pragma unroll
        for (int mi = 0; mi < 4; ++mi)
#pragma unroll
            for (int ni = 0; ni < 4; ++ni) {
                int col = n0 + wc * 64 + ni * 16 + lq;
                int c2  = col - 1536;
                int hh  = c2 >> 6, dd = c2 & 63;
                int row = m0 + wr * 64 + mi * 16 + g * 4;
                int bb  = row >> 10, tr = row & 1023;
                float bv = bias[col];
                ushort4 o;
                o.x = f2bf(acc[mi][ni][0] + bv);
                o.y = f2bf(acc[mi][ni][1] + bv);
                o.z = f2bf(acc[mi][ni][2] + bv);
                o.w = f2bf(acc[mi][ni][3] + bv);
                *(ushort4*)&vt[(((size_t)bb * Hh + hh) * Dd + dd) * Tt + tr] = o;
            }
        return;
    }

#pragma unroll
    for (int mi = 0; mi < 4; ++mi)
#pragma unroll
        for (int ni = 0; ni < 4; ++ni) {
            int col = n0 + wc * 64 + ni * 16 + lq;
            if (col >= N) continue;
            int row = m0 + wr * 64 + mi * 16 + g * 4;
            float bv = bias ? bias[col] : 0.f;
#pragma unroll
            for (int q = 0; q < 4; ++q) {
                float v = acc[mi][ni][q] + bv;
                size_t o = (size_t)(row + q) * N + col;
                if (EPI == 1) v += resid[o];
                if (EPI == 2) v = gelu_f(v);
                st_out(out, o, v);
            }
        }
}

// ---------------------------------------------------------------------------
// 64x128 bf16 GEMM, BK=64, packed-B, row-major A (proj/fc2), SWAPPED
// operands: mfma(B,A) -> lane holds 4 consecutive n for one m -> float4
// epilogue stores + float4 resid/bias loads. Double-buffered 48 KB.
// ---------------------------------------------------------------------------
__global__ __launch_bounds__(256)
void gemm_n64(const u16* __restrict__ A, const u16* __restrict__ Wp,
              const float* __restrict__ bias, const float* __restrict__ resid,
              float* __restrict__ out, int N, int K)
{
    __shared__ uint4 AF[2][8][64];    // [buf][mt*2+slab]  16 KB
    __shared__ uint4 BF[2][16][64];   // [buf][nt*2+slab]  32 KB
    const int tid  = threadIdx.x;
    const int lane = tid & 63;
    const int w    = tid >> 6;
    const int wr   = w & 1, wc = w >> 1;
    const int lq   = lane & 15, g = lane >> 4;
    const int m0   = blockIdx.x * 64, n0 = blockIdx.y * 128;
    const int KB   = K >> 5;
    const int nk   = K >> 6;

    const u16* ap = A + (size_t)(m0 + w * 16 + lq) * K + g * 8;
    int tn0 = (n0 >> 4) + 2 * w, tn1 = tn0 + 1;
    const int tmax = (N >> 4) - 1;
    tn0 = tn0 < tmax ? tn0 : tmax;
    tn1 = tn1 < tmax ? tn1 : tmax;
    const u16* bq0 = Wp + (((size_t)tn0 * KB) << 9) + lane * 8;
    const u16* bq1 = Wp + (((size_t)tn1 * KB) << 9) + lane * 8;

    f32x4 acc[2][4] = {};

#define GSTAGE(t, bi) do {                                                 \
        gload16(ap + ((t) << 6),      &AF[bi][2 * w][lane]);               \
        gload16(ap + ((t) << 6) + 32, &AF[bi][2 * w + 1][lane]);           \
        gload16(bq0 + ((size_t)(2 * (t)) << 9),     &BF[bi][4 * w][lane]); \
        gload16(bq0 + ((size_t)(2 * (t) + 1) << 9), &BF[bi][4 * w + 1][lane]); \
        gload16(bq1 + ((size_t)(2 * (t)) << 9),     &BF[bi][4 * w + 2][lane]); \
        gload16(bq1 + ((size_t)(2 * (t) + 1) << 9), &BF[bi][4 * w + 3][lane]); } while (0)

    GSTAGE(0, 0);
    WAITVM(0);
    SCHEDB();
    SBAR();
    SCHEDB();

    for (int t = 0; t < nk; ++t) {
        const int buf = t & 1;
        if (t + 1 < nk) GSTAGE(t + 1, buf ^ 1);

#pragma unroll
        for (int s = 0; s < 2; ++s) {
            bf16x8 a0 = __builtin_bit_cast(bf16x8, AF[buf][(wr * 2) * 2 + s][lane]);
            bf16x8 a1 = __builtin_bit_cast(bf16x8, AF[buf][(wr * 2 + 1) * 2 + s][lane]);
            bf16x8 bb[4];
#pragma unroll
            for (int ni = 0; ni < 4; ++ni)
                bb[ni] = __builtin_bit_cast(bf16x8, BF[buf][(wc * 4 + ni) * 2 + s][lane]);
            __builtin_amdgcn_s_setprio(1);
#pragma unroll
            for (int ni = 0; ni < 4; ++ni) {
                acc[0][ni] = __builtin_amdgcn_mfma_f32_16x16x32_bf16(
                    bb[ni], a0, acc[0][ni], 0, 0, 0);
                acc[1][ni] = __builtin_amdgcn_mfma_f32_16x16x32_bf16(
                    bb[ni], a1, acc[1][ni], 0, 0, 0);
            }
            __builtin_amdgcn_s_setprio(0);
        }

        WAITVM(0);     // own 6 staged loads; issued a full phase earlier
        SCHEDB();
        SBAR();
        SCHEDB();
    }
#undef GSTAGE

    // swapped epilogue: lane (lq,g) holds n = n0+wc*64+ni*16+g*4..+3 of
    // row m = m0+(wr*2+mi)*16+lq  ->  one float4 store per fragment.
#pragma unroll
    for (int mi = 0; mi < 2; ++mi)
#pragma unroll
        for (int ni = 0; ni < 4; ++ni) {
            int m = m0 + (wr * 2 + mi) * 16 + lq;
            int n = n0 + wc * 64 + ni * 16 + (g << 2);
            float4 bv = *(const float4*)&bias[n];
            size_t o = (size_t)m * N + n;
            float4 rv = *(const float4*)&resid[o];
            float4 v;
            v.x = acc[mi][ni][0] + bv.x + rv.x;
            v.y = acc[mi][ni][1] + bv.y + rv.y;
            v.z = acc[mi][ni][2] + bv.z + rv.z;
            v.w = acc[mi][ni][3] + bv.w + rv.w;
            *(float4*)&out[o] = v;
        }
}

// ---------------------------------------------------------------------------
// 256x256 8-phase bf16 GEMM, packed-A + packed-B, SWAPPED operands —
// lm_head only. Epilogue: float4 stores (N-tail guarded).
// ---------------------------------------------------------------------------
__global__ __launch_bounds__(512, 2)
void gemm8p(const u16* __restrict__ Apk, const u16* __restrict__ Wp,
            float* __restrict__ out, int N, int K)
{
    __shared__ uint4 AF[2][16][2][64];
    __shared__ uint4 BF[2][16][2][64];
    const int tid  = threadIdx.x;
    const int lane = tid & 63;
    const int w    = tid >> 6;
    const int wr   = w >> 2, wc = w & 3;
    const int lq   = lane & 15, g = lane >> 4;
    const int m0   = blockIdx.x * 256, n0 = blockIdx.y * 256;
    const int KB   = K >> 5;

    const u16* aq0 = Apk + ((((size_t)(m0 >> 4) + 2 * w) * KB) << 9) + lane * 8;
    const u16* aq1 = aq0 + ((size_t)KB << 9);

    int tn0 = (n0 >> 4) + 2 * w, tn1 = tn0 + 1;
    const int tmax = (N >> 4) - 1;
    tn0 = tn0 < tmax ? tn0 : tmax;
    tn1 = tn1 < tmax ? tn1 : tmax;
    const u16* bq0 = Wp + (((size_t)tn0 * KB) << 9) + lane * 8;
    const u16* bq1 = Wp + (((size_t)tn1 * KB) << 9) + lane * 8;

    f32x4 acc[8][4] = {};
    const int nt = K >> 6;

    gload16(aq0,       &AF[0][2 * w][0][lane]);
    gload16(aq1,       &AF[0][2 * w + 1][0][lane]);
    gload16(bq0,       &BF[0][2 * w][0][lane]);
    gload16(bq1,       &BF[0][2 * w + 1][0][lane]);
    gload16(aq0 + 512, &AF[0][2 * w][1][lane]);
    gload16(aq1 + 512, &AF[0][2 * w + 1][1][lane]);
    gload16(bq0 + 512, &BF[0][2 * w][1][lane]);
    gload16(bq1 + 512, &BF[0][2 * w + 1][1][lane]);
    WAITVM(0);
    SCHEDB();
    SBAR();

    int buf = 0;
    for (int t = 0; t < nt; ++t) {
        const bool more = (t + 1 < nt);
        const size_t bb0 = (size_t)(2 * (t + 1)) << 9;
        bf16x8 a0[4], a1[4], b0[4];

#pragma unroll
        for (int i = 0; i < 4; ++i)
            a0[i] = __builtin_bit_cast(bf16x8, AF[buf][wr * 8 + i][0][lane]);
#pragma unroll
        for (int i = 0; i < 4; ++i)
            b0[i] = __builtin_bit_cast(bf16x8, BF[buf][wc * 4 + i][0][lane]);
        if (more) {
            gload16(aq0 + bb0, &AF[buf ^ 1][2 * w][0][lane]);
            gload16(aq1 + bb0, &AF[buf ^ 1][2 * w + 1][0][lane]);
        }
        SCHEDB();
        SBAR();
        WAITLGKM0();
        SCHEDB();
        __builtin_amdgcn_s_setprio(1);
#pragma unroll
        for (int mi = 0; mi < 4; ++mi)
#pragma unroll
            for (int ni = 0; ni < 4; ++ni)
                acc[mi][ni] = __builtin_amdgcn_mfma_f32_16x16x32_bf16(
                    b0[ni], a0[mi], acc[mi][ni], 0, 0, 0);
        __builtin_amdgcn_s_setprio(0);
        SBAR();

#pragma unroll
        for (int i = 0; i < 4; ++i)
            a1[i] = __builtin_bit_cast(bf16x8, AF[buf][wr * 8 + 4 + i][0][lane]);
        if (more) {
            gload16(bq0 + bb0, &BF[buf ^ 1][2 * w][0][lane]);
            gload16(bq1 + bb0, &BF[buf ^ 1][2 * w + 1][0][lane]);
        }
        SCHEDB();
        SBAR();
        WAITLGKM0();
        SCHEDB();
        __builtin_amdgcn_s_setprio(1);
#pragma unroll
        for (int mi = 0; mi < 4; ++mi)
#pragma unroll
            for (int ni = 0; ni < 4; ++ni)
                acc[4 + mi][ni] = __builtin_amdgcn_mfma_f32_16x16x32_bf16(
                    b0[ni], a1[mi], acc[4 + mi][ni], 0, 0, 0);
        __builtin_amdgcn_s_setprio(0);
        if (more) { WAITVM(4); } else { WAITVM(0); }
        SCHEDB();
        SBAR();

#pragma unroll
        for (int i = 0; i < 4; ++i)
            a0[i] = __builtin_bit_cast(bf16x8, AF[buf][wr * 8 + i][1][lane]);
#pragma unroll
        for (int i = 0; i < 4; ++i)
            b0[i] = __builtin_bit_cast(bf16x8, BF[buf][wc * 4 + i][1][lane]);
        if (more) {
            gload16(aq0 + bb0 + 512, &AF[buf ^ 1][2 * w][1][lane]);
            gload16(aq1 + bb0 + 512, &AF[buf ^ 1][2 * w + 1][1][lane]);
        }
        SCHEDB();
        SBAR();
        WAITLGKM0();
        SCHEDB();
        __builtin_amdgcn_s_setprio(1);
#pragma unroll
        for (int mi = 0; mi < 4; ++mi)
#pragma unroll
            for (int ni = 0; ni < 4; ++ni)
                acc[mi][ni] = __builtin_amdgcn_mfma_f32_16x16x32_bf16(
                    b0[ni], a0[mi], acc[mi][ni], 0, 0, 0);
        __builtin_amdgcn_s_setprio(0);
        SBAR();

#pragma unroll
        for (int i = 0; i < 4; ++i)
            a1[i] = __builtin_bit_cast(bf16x8, AF[buf][wr * 8 + 4 + i][1][lane]);
        if (more) {
            gload16(bq0 + bb0 + 512, &BF[buf ^ 1][2 * w][1][lane]);
            gload16(bq1 + bb0 + 512, &BF[buf ^ 1][2 * w + 1][1][lane]);
        }
        SCHEDB();
        SBAR();
        WAITLGKM0();
        SCHEDB();
        __builtin_amdgcn_s_setprio(1);
#pragma unroll
        for (int mi = 0; mi < 4; ++mi)
#pragma unroll
            for (int ni = 0; ni < 4; ++ni)
                acc[4 + mi][ni] = __builtin_amdgcn_mfma_f32_16x16x32_bf16(
                    b0[ni], a1[mi], acc[4 + mi][ni], 0, 0, 0);
        __builtin_amdgcn_s_setprio(0);
        if (more) { WAITVM(4); } else { WAITVM(0); }
        SCHEDB();
        SBAR();

        buf ^= 1;
    }

    // swapped epilogue: lane (lq,g) holds n = n0+wc*64+ni*16+g*4..+3 of
    // row m = m0+wr*128+mi*16+lq -> float4 store (tail-guarded, N=10000).
#pragma unroll
    for (int mi = 0; mi < 8; ++mi)
#pragma unroll
        for (int ni = 0; ni < 4; ++ni) {
            int m = m0 + wr * 128 + mi * 16 + lq;
            int n = n0 + wc * 64 + ni * 16 + (g << 2);
            size_t o = (size_t)m * N + n;
            if (n + 3 < N) {
                float4 v;
                v.x = acc[mi][ni][0]; v.y = acc[mi][ni][1];
                v.z = acc[mi][ni][2]; v.w = acc[mi][ni][3];
                *(float4*)&out[o] = v;
            } else {
#pragma unroll
                for (int q = 0; q < 4; ++q)
                    if (n + q < N) out[o + q] = acc[mi][ni][q];
            }
        }
}

// ---------------------------------------------------------------------------
// MFMA flash attention, QBLK=128 / 8 waves, swapped QK^T (r13/r15 version).
// ---------------------------------------------------------------------------
__global__ __launch_bounds__(512)
void attn_mfma(const u16* __restrict__ qkv, const u16* __restrict__ vt,
               u16* __restrict__ y)
{
    __shared__ uint4 KF[2][4][2][64];
    __shared__ uint4 VF[2][4][2][64];

    const int tid  = threadIdx.x;
    const int lane = tid & 63;
    const int w    = tid >> 6;
    const int lq   = lane & 15, g = lane >> 4;
    const int m    = gridDim.x - 1 - blockIdx.x;   // heavy blocks first
    const int bh   = blockIdx.y;
    const int b    = bh / Hh, h = bh % Hh;
    const int wq0  = m * 128 + w * 16;
    const size_t base = (size_t)b * Tt * (3 * Cc);

    const u16* qrow = qkv + base + (size_t)(wq0 + lq) * (3 * Cc) + h * Dd;
    bf16x8 qf0 = __builtin_bit_cast(bf16x8, *(const uint4*)(qrow + g * 8));
    bf16x8 qf1 = __builtin_bit_cast(bf16x8, *(const uint4*)(qrow + 32 + g * 8));

    f32x4 yac[4] = {};
    float lrun = 0.f;

    const int wm = w & 3;
    const u16* kbase = qkv + base + Cc + h * Dd + (size_t)(wm * 16 + lq) * (3 * Cc) + g * 8;
    const u16* vbase = vt + ((size_t)bh * Dd + wm * 16 + lq) * Tt + g * 8;

#define STAGE(c, bi)  do {                                              \
        if (w < 4) {                                                    \
            const u16* kp = kbase + (size_t)(c) * 64 * (3 * Cc);        \
            gload16(kp,      &KF[bi][wm][0][lane]);                     \
            gload16(kp + 32, &KF[bi][wm][1][lane]);                     \
        } else {                                                        \
            const u16* vp = vbase + (c) * 64;                           \
            gload16(vp,      &VF[bi][wm][0][lane]);                     \
            gload16(vp + 32, &VF[bi][wm][1][lane]);                     \
        }                                                               \
    } while (0)

    const int nch = 2 * m + 2;
    STAGE(0, 0);
    WAITVM(0);
    SCHEDB();
    SBAR();

    const int srcb = lq + ((g & 1) << 5);

    int buf = 0;
    for (int c = 0; c < nch; ++c) {
        if (c + 1 < nch) STAGE(c + 1, buf ^ 1);

        f32x4 sc[4] = {};
        __builtin_amdgcn_s_setprio(1);
#pragma unroll
        for (int nt = 0; nt < 4; ++nt) {
            bf16x8 k0 = __builtin_bit_cast(bf16x8, KF[buf][nt][0][lane]);
            bf16x8 k1 = __builtin_bit_cast(bf16x8, KF[buf][nt][1][lane]);
            sc[nt] = __builtin_amdgcn_mfma_f32_16x16x32_bf16(k0, qf0, sc[nt], 0, 0, 0);
            sc[nt] = __builtin_amdgcn_mfma_f32_16x16x32_bf16(k1, qf1, sc[nt], 0, 0, 0);
        }
        __builtin_amdgcn_s_setprio(0);

        const int s0 = c * 64;
        if (s0 + 63 > wq0) {
            const int qg = wq0 + lq;
#pragma unroll
            for (int nt = 0; nt < 4; ++nt) {
                const int kb = s0 + nt * 16 + (g << 2);
#pragma unroll
                for (int j = 0; j < 4; ++j)
                    if (kb + j > qg) sc[nt][j] = -1e30f;
            }
        }

        float ls = 0.f;
#pragma unroll
        for (int nt = 0; nt < 4; ++nt)
#pragma unroll
            for (int j = 0; j < 4; ++j) {
                float p = fast_exp2(sc[nt][j]);
                sc[nt][j] = p;
                ls += p;
            }
        ls += __shfl_xor(ls, 16);
        ls += __shfl_xor(ls, 32);
        lrun += ls;

        unsigned pk[4][2];
#pragma unroll
        for (int nt = 0; nt < 4; ++nt) {
            unsigned u0 = __float_as_uint(sc[nt][0]);
            unsigned u1 = __float_as_uint(sc[nt][1]);
            unsigned u2 = __float_as_uint(sc[nt][2]);
            unsigned u3 = __float_as_uint(sc[nt][3]);
            pk[nt][0] = (u0 >> 16) | (u1 & 0xffff0000u);
            pk[nt][1] = (u2 >> 16) | (u3 & 0xffff0000u);
        }

        unsigned pa0[4], pa1[4];
#pragma unroll
        for (int m2 = 0; m2 < 4; ++m2) {
            int hsel = m2 & 1;
            int src  = srcb + ((m2 >> 1) << 4);
            unsigned lo0 = __shfl(pk[0][hsel], src);
            unsigned hi0 = __shfl(pk[1][hsel], src);
            unsigned lo1 = __shfl(pk[2][hsel], src);
            unsigned hi1 = __shfl(pk[3][hsel], src);
            pa0[m2] = (g >> 1) ? hi0 : lo0;
            pa1[m2] = (g >> 1) ? hi1 : lo1;
        }
        uint4 A0 = make_uint4(pa0[0], pa0[1], pa0[2], pa0[3]);
        uint4 A1 = make_uint4(pa1[0], pa1[1], pa1[2], pa1[3]);
        bf16x8 pA0 = __builtin_bit_cast(bf16x8, A0);
        bf16x8 pA1 = __builtin_bit_cast(bf16x8, A1);

        __builtin_amdgcn_s_setprio(1);
#pragma unroll
        for (int dt = 0; dt < 4; ++dt) {
            bf16x8 vb0 = __builtin_bit_cast(bf16x8, VF[buf][dt][0][lane]);
            bf16x8 vb1 = __builtin_bit_cast(bf16x8, VF[buf][dt][1][lane]);
            yac[dt] = __builtin_amdgcn_mfma_f32_16x16x32_bf16(pA0, vb0, yac[dt], 0, 0, 0);
            yac[dt] = __builtin_amdgcn_mfma_f32_16x16x32_bf16(pA1, vb1, yac[dt], 0, 0, 0);
        }
        __builtin_amdgcn_s_setprio(0);

        if (c + 1 < nch) { WAITVM(0); }
        SCHEDB();
        SBAR();
        buf ^= 1;
    }
#undef STAGE

    f32x4 rl;
#pragma unroll
    for (int j = 0; j < 4; ++j)
        rl[j] = 1.0f / __shfl(lrun, (g << 2) + j);
#pragma unroll
    for (int dt = 0; dt < 4; ++dt)
#pragma unroll
        for (int j = 0; j < 4; ++j)
            y[(size_t)(b * Tt + wq0 + (g << 2) + j) * Cc + h * Dd + dt * 16 + lq]
                = f2bf(yac[dt][j] * rl[j]);
}

// ---------------------------------------------------------------------------
// tpred (packed-A hB): out[row] = dot(h[row], tp_w)
// ---------------------------------------------------------------------------
__global__ __launch_bounds__(256)
void tpred_kernel(const u16* __restrict__ hp, const float* __restrict__ tp,
                  float* __restrict__ out)
{
    const int row  = blockIdx.x * 4 + (threadIdx.x >> 6);
    const int lane = threadIdx.x & 63;
    const int tile = row >> 4, r15 = row & 15;
    const u16* tb = hp + ((size_t)tile * 24 << 9);
    float s = 0.f;
#pragma unroll
    for (int j = 0; j < 12; ++j) {
        int col = lane + (j << 6);
        int kt = col >> 5, g = (col >> 3) & 3, e = col & 7;
        s += bf2f(tb[((size_t)kt << 9) + (r15 | (g << 4)) * 8 + e]) * tp[col];
    }
#pragma unroll
    for (int m = 32; m; m >>= 1) s += __shfl_xor(s, m);
    if (lane == 0) out[row] = s;
}

// ---------------------------------------------------------------------------
extern "C" void kernel_launch(void* const* d_in, const int* in_sizes, int n_in,
                              void* d_out, int out_size, void* d_ws, size_t ws_size,
                              hipStream_t stream)
{
    const int*   idx  = (const int*)d_in[0];
    const float* ts   = (const float*)d_in[1];
    const float* wte  = (const float*)d_in[2];
    const float* freq = (const float*)d_in[3];
    const float* ph   = (const float*)d_in[4];
    const float* wpe  = (const float*)d_in[5];
    const float* ln1w = (const float*)d_in[6];
    const float* ln1b = (const float*)d_in[7];
    const float* qkvw = (const float*)d_in[8];
    const float* qkvb = (const float*)d_in[9];
    const float* pw   = (const float*)d_in[10];
    const float* pb   = (const float*)d_in[11];
    const float* ln2w = (const float*)d_in[12];
    const float* ln2b = (const float*)d_in[13];
    const float* fcw  = (const float*)d_in[14];
    const float* fcb  = (const float*)d_in[15];
    const float* f2w  = (const float*)d_in[16];
    const float* f2b  = (const float*)d_in[17];
    const float* lnfw = (const float*)d_in[18];
    const float* lnfb = (const float*)d_in[19];
    const float* lmw  = (const float*)d_in[20];
    const float* tpw  = (const float*)d_in[21];
    float* out = (float*)d_out;

    const int n_qkvw = 3 * Cc * Cc, n_pw = Cc * Cc, n_fcw = 4 * Cc * Cc;

    // ---- workspace layout ----
    char* p = (char*)d_ws;
    float* x    = (float*)p;               p += (size_t)MTOT * Cc * 4;
    u16*   qkvB = (u16*)p;                 p += (size_t)MTOT * 3 * Cc * 2;
    u16*   VtB  = (u16*)p;                 p += (size_t)Bb * Hh * Dd * Tt * 2;
    u16*   hB   = (u16*)p;                 p += (size_t)MTOT * Cc * 2;   // packed
    u16*   yB   = (u16*)p;                 p += (size_t)MTOT * Cc * 2;
    u16*   mbB  = (u16*)p;                 p += (size_t)MTOT * 4 * Cc * 2;
    u16*   lmwB = (u16*)p;                 p += (size_t)Vv * Cc * 2;
    float* sbias= (float*)p;               p += (size_t)Ll * 3 * Cc * 4;
    char* wbase = p;

    size_t need_big = (size_t)(wbase - (char*)d_ws)
                    + ((size_t)Ll * (n_qkvw + n_pw + 2 * n_fcw)) * 2;
    bool big = ws_size >= need_big;

    u16 *wqA, *wpA, *wfA, *wf2A;
    if (big) {
        wqA  = (u16*)wbase;                wbase += (size_t)Ll * n_qkvw * 2;
        wpA  = (u16*)wbase;                wbase += (size_t)Ll * n_pw * 2;
        wfA  = (u16*)wbase;                wbase += (size_t)Ll * n_fcw * 2;
        wf2A = (u16*)wbase;
    } else {
        wqA  = (u16*)wbase;                wbase += (size_t)n_qkvw * 2;
        wpA  = (u16*)wbase;                wbase += (size_t)n_pw * 2;
        wfA  = (u16*)wbase;                wbase += (size_t)n_fcw * 2;
        wf2A = (u16*)wbase;
    }

    auto pack = [&](const float* src, u16* dst, size_t rows, int K,
                    int rowmod, int scaleLim) {
        int nk8 = (int)(rows * K / 8);
        convert_pack<<<(nk8 + 255) / 256, 256, 0, stream>>>(
            src, dst, nk8, K, rowmod, scaleLim);
    };

    pack(lmw, lmwB, Vv, Cc, 0, 0);
    {
        int nb = Ll * 3 * Cc;
        scale_qkvb<<<(nb + 255) / 256, 256, 0, stream>>>(qkvb, sbias, nb);
    }
    if (big) {
        pack(qkvw, wqA,  (size_t)Ll * 3 * Cc, Cc, 3 * Cc, Cc);
        pack(pw,   wpA,  (size_t)Ll * Cc,     Cc, 0, 0);
        pack(fcw,  wfA,  (size_t)Ll * 4 * Cc, Cc, 0, 0);
        pack(f2w,  wf2A, (size_t)Ll * Cc, 4 * Cc, 0, 0);
    }
    embed_kernel<<<MTOT, 256, 0, stream>>>(idx, ts, wte, freq, ph, wpe, x);

    for (int l = 0; l < Ll; ++l) {
        u16 *wqB, *wpB, *wfB, *wf2B;
        if (big) {
            wqB  = wqA  + (size_t)l * n_qkvw;
            wpB  = wpA  + (size_t)l * n_pw;
            wfB  = wfA  + (size_t)l * n_fcw;
            wf2B = wf2A + (size_t)l * n_fcw;
        } else {
            wqB = wqA; wpB = wpA; wfB = wfA; wf2B = wf2A;
            pack(qkvw + (size_t)l * n_qkvw, wqB, 3 * Cc, Cc, 3 * Cc, Cc);
            pack(pw   + (size_t)l * n_pw,   wpB, Cc,     Cc, 0, 0);
            pack(fcw  + (size_t)l * n_fcw,  wfB, 4 * Cc, Cc, 0, 0);
            pack(f2w  + (size_t)l * n_fcw,  wf2B, Cc, 4 * Cc, 0, 0);
        }

        ln_pack16<<<MTOT / 16, 256, 0, stream>>>(x, ln1w + l * Cc, ln1b + l * Cc, hB);
        gemm_bf16<3, 1, u16><<<dim3(32, 18), 256, 0, stream>>>(
            hB, wqB, sbias + (size_t)l * 3 * Cc, nullptr, qkvB, VtB, 3 * Cc, Cc);
        attn_mfma<<<dim3(Tt / 128, Bb * Hh), 512, 0, stream>>>(qkvB, VtB, yB);
        gemm_n64<<<dim3(64, 6), 256, 0, stream>>>(
            yB, wpB, pb + (size_t)l * Cc, x, x, Cc, Cc);
        ln_pack16<<<MTOT / 16, 256, 0, stream>>>(x, ln2w + l * Cc, ln2b + l * Cc, hB);
        gemm_bf16<2, 1, u16><<<dim3(32, 24), 256, 0, stream>>>(
            hB, wfB, fcb + (size_t)l * 4 * Cc, nullptr, mbB, nullptr, 4 * Cc, Cc);
        gemm_n64<<<dim3(64, 6), 256, 0, stream>>>(
            mbB, wf2B, f2b + (size_t)l * Cc, x, x, Cc, 4 * Cc);
    }

    ln_pack16<<<MTOT / 16, 256, 0, stream>>>(x, lnfw, lnfb, hB);
    gemm8p<<<dim3(16, 40), 512, 0, stream>>>(hB, lmwB, out, Vv, Cc);
    tpred_kernel<<<MTOT / 4, 256, 0, stream>>>(hB, tpw, out + (size_t)MTOT * Vv);
}